// Round 13
// baseline (4187.135 us; speedup 1.0000x reference)
//
#include <hip/hip_runtime.h>
#include <hip/hip_bf16.h>
#include <math.h>

// Problem dims
#define BB   128   // batch
#define SS   128   // sequence / positions
#define HH   256   // hidden
#define DYNN 192   // dynamic channels
#define LC   128   // W_hh rows cached in LDS (rows 0..LC-1)

// ws layout (float offsets)
#define OFF_FLAG  0
#define OFF_G     64
#define OFF_G0    (OFF_G + 1536)
#define OFF_M1A   (OFF_G0 + 768)
#define OFF_CA    (OFF_M1A + 512)
#define OFF_M1P   (OFF_CA + 256)
#define OFF_CP    (OFF_M1P + 512)
#define OFF_M3P   (OFF_CP + 256)
#define OFF_CP3   (OFF_M3P + 512)
#define OFF_LM    (OFF_CP3 + 256)
#define OFF_M2A   (OFF_LM + 16384)
#define OFF_M2P   (OFF_M2A + 49152)
#define OFF_BASEA (OFF_M2P + 49152)
#define OFF_BASEP (OFF_BASEA + 4194304)
#define OFF_END   (OFF_BASEP + 4194304)

__device__ __forceinline__ float tanh_fast(float x) {
    float e = __builtin_amdgcn_exp2f(x * 2.885390081777927f); // 2*log2(e)
    return 1.0f - 2.0f * __builtin_amdgcn_rcpf(e + 1.0f);
}

// Y-group spin barrier: monotone LDS counter, wave leaders add 1. (proven R3/R5/R6)
__device__ __forceinline__ void ybar(int* cnt, bool arrive, int target) {
    if (arrive && (threadIdx.x & 63) == 0)
        __hip_atomic_fetch_add(cnt, 1, __ATOMIC_RELEASE, __HIP_MEMORY_SCOPE_WORKGROUP);
    while (__hip_atomic_load(cnt, __ATOMIC_ACQUIRE, __HIP_MEMORY_SCOPE_WORKGROUP) < target)
        __builtin_amdgcn_s_sleep(1);
}

// K1: logmask + "dynamic is nonzero" flag
__global__ void k1_logmask(const float* __restrict__ dyn, float* __restrict__ lm,
                           int* __restrict__ flag) {
    int g = blockIdx.x * 256 + threadIdx.x;
    if (g >= BB * SS) return;
    int b = g >> 7, s = g & 127;
    const float* p = dyn + (size_t)b * DYNN * SS + s;
    float mv = 0.f, m1 = 0.f, m2 = 0.f;
    bool nz = false;
    for (int i = 0; i < 64; ++i)        { float v = p[(size_t)i * SS]; mv += v; nz |= (v != 0.f); }
    for (int i = 64; i < 128; ++i)      { float v = p[(size_t)i * SS]; m1 += v; nz |= (v != 0.f); }
    for (int i = 128; i < 192; ++i)     { float v = p[(size_t)i * SS]; m2 += v; nz |= (v != 0.f); }
    float dm = m1 * m2 + mv;
    lm[g] = (dm != 0.f) ? -__builtin_inff() : 0.f;
    if (nz) atomicOr(flag, 1);
}

// K0a: small weight folds (rank-2 eliminations)
__global__ void k0a_folds(const float* __restrict__ Wih, const float* __restrict__ bih,
                          const float* __restrict__ dW,  const float* __restrict__ db,
                          const float* __restrict__ aW,  const float* __restrict__ pW,
                          const float* __restrict__ esW, const float* __restrict__ esb,
                          const float* __restrict__ edb, float* __restrict__ wsf) {
    int idx = blockIdx.x * 256 + threadIdx.x;
    float* G   = wsf + OFF_G;
    float* g0  = wsf + OFF_G0;
    float* M1a = wsf + OFF_M1A;
    float* ca  = wsf + OFF_CA;
    float* M1p = wsf + OFF_M1P;
    float* cp  = wsf + OFF_CP;
    float* M3p = wsf + OFF_M3P;
    float* cp3 = wsf + OFF_CP3;
    if (idx < 1536) {
        int r = idx >> 1, j = idx & 1;
        float a = 0.f;
        for (int k = 0; k < 256; ++k) a += Wih[r * 256 + k] * dW[k * 2 + j];
        G[idx] = a;
    } else if (idx < 2304) {
        int r = idx - 1536;
        float a = 0.f;
        for (int k = 0; k < 256; ++k) a += Wih[r * 256 + k] * db[k];
        g0[r] = a + bih[r];
    } else if (idx < 2816) {
        int t = idx - 2304; int h = t >> 1, j = t & 1;
        float a = 0.f;
        for (int k = 0; k < 256; ++k) a += aW[h * 768 + k] * esW[k * 2 + j];
        M1a[t] = a;
    } else if (idx < 3072) {
        int h = idx - 2816;
        float a = 0.f, b2 = 0.f;
        for (int k = 0; k < 256; ++k) a  += aW[h * 768 + k]       * esb[k];
        for (int k = 0; k < 256; ++k) b2 += aW[h * 768 + 256 + k] * edb[k];
        ca[h] = a + b2;
    } else if (idx < 3584) {
        int t = idx - 3072; int h = t >> 1, j = t & 1;
        float a = 0.f;
        for (int k = 0; k < 256; ++k) a += pW[h * 768 + k] * esW[k * 2 + j];
        M1p[t] = a;
    } else if (idx < 3840) {
        int h = idx - 3584;
        float a = 0.f, b2 = 0.f;
        for (int k = 0; k < 256; ++k) a  += pW[h * 768 + k]       * esb[k];
        for (int k = 0; k < 256; ++k) b2 += pW[h * 768 + 256 + k] * edb[k];
        cp[h] = a + b2;
    } else if (idx < 4352) {
        int t = idx - 3840; int h = t >> 1, j = t & 1;
        float a = 0.f;
        for (int k = 0; k < 256; ++k) a += pW[h * 768 + 512 + k] * esW[k * 2 + j];
        M3p[t] = a;
    } else if (idx < 4608) {
        int h = idx - 4352;
        float a = 0.f;
        for (int k = 0; k < 256; ++k) a += pW[h * 768 + 512 + k] * esb[k];
        cp3[h] = a;
    }
}

// K0b: M2a/M2p folds for the general (dynamic != 0) path
__global__ void k0b_m2(const float* __restrict__ aW, const float* __restrict__ pW,
                       const float* __restrict__ edW, float* __restrict__ wsf,
                       const int* __restrict__ flag) {
    if (*flag == 0) return;
    int idx = blockIdx.x * 256 + threadIdx.x;
    if (idx >= 2 * 49152) return;
    int which = idx / 49152;
    int t = idx % 49152;
    int h = t / DYNN, i = t % DYNN;
    const float* W = which ? pW : aW;
    float a = 0.f;
    for (int k = 0; k < 256; ++k) a += W[h * 768 + 256 + k] * edW[k * DYNN + i];
    wsf[(which ? OFF_M2P : OFF_M2A) + t] = a;
}

// K2: general-path bases, layout [b][s][h]
__global__ void k2_bases(const float* __restrict__ stat, const float* __restrict__ dyn,
                         float* __restrict__ wsf, const int* __restrict__ flag) {
    if (*flag == 0) return;
    __shared__ float col[DYNN];
    __shared__ float s01[2];
    const float* M1a = wsf + OFF_M1A; const float* ca  = wsf + OFF_CA;
    const float* M1p = wsf + OFF_M1P; const float* cp  = wsf + OFF_CP;
    const float* M2a = wsf + OFF_M2A; const float* M2p = wsf + OFF_M2P;
    float* basea = wsf + OFF_BASEA;   float* basep = wsf + OFF_BASEP;
    for (int pair = blockIdx.x; pair < BB * SS; pair += gridDim.x) {
        int b = pair >> 7, s = pair & 127;
        if (threadIdx.x < DYNN) col[threadIdx.x] = dyn[((size_t)b * DYNN + threadIdx.x) * SS + s];
        if (threadIdx.x == DYNN) {
            s01[0] = stat[((size_t)b * 3 + 1) * SS + s];
            s01[1] = stat[((size_t)b * 3 + 2) * SS + s];
        }
        __syncthreads();
        int h = threadIdx.x;
        float aa = fmaf(M1a[h * 2], s01[0], fmaf(M1a[h * 2 + 1], s01[1], ca[h]));
        float pp = fmaf(M1p[h * 2], s01[0], fmaf(M1p[h * 2 + 1], s01[1], cp[h]));
        for (int i = 0; i < DYNN; ++i) {
            aa = fmaf(M2a[h * DYNN + i], col[i], aa);
            pp = fmaf(M2p[h * DYNN + i], col[i], pp);
        }
        basea[((size_t)b * SS + s) * HH + h] = aa;
        basep[((size_t)b * SS + s) * HH + h] = pp;
        __syncthreads();
    }
}

// Row dot-product: fmaf nest order bitwise identical across all rounds.
#define DOT16(W0, W1, W2, W3)                                                                    \
    float acc = 0.f;                                                                             \
    acc = fmaf(W0.x, hx0.x, fmaf(W0.y, hx0.y, fmaf(W0.z, hx0.z, fmaf(W0.w, hx0.w, acc))));       \
    acc = fmaf(W1.x, hx1.x, fmaf(W1.y, hx1.y, fmaf(W1.z, hx1.z, fmaf(W1.w, hx1.w, acc))));       \
    acc = fmaf(W2.x, hx2.x, fmaf(W2.y, hx2.y, fmaf(W2.z, hx2.z, fmaf(W2.w, hx2.w, acc))));       \
    acc = fmaf(W3.x, hx3.x, fmaf(W3.y, hx3.y, fmaf(W3.z, hx3.z, fmaf(W3.w, hx3.w, acc))));       \
    acc += __shfl_xor(acc, 1, 16); acc += __shfl_xor(acc, 2, 16);                                \
    acc += __shfl_xor(acc, 4, 16); acc += __shfl_xor(acc, 8, 16);

// K3: sequential decoder, one WG per batch (grid=128, 1024 threads).
//   waves 0-7  (X): gh(t+1) = W_hh*h; rows 0..127 from LDS cache, rest from L2
//     via MANUAL 4-deep ping-pong register pipeline (A/B/C/D buffer sets).
//   waves 8-15 (Y): t1=A3*h (same 4-deep pipeline) -> attn -> softmax -> ptr
//     -> argmax (ybar-chained).
// R13 = R11 + manual prefetch: R12 showed the compiler won't keep >4 float4
// in flight per wave on its own (VGPR stayed 64; unroll pragma neutral).
// Measured X stream ~2.6 B/cy/wave = depth-limited; 4 named buffers (64 VGPR)
// give each refill ~3 compute blocks (~200cy) of slack.
__global__ __launch_bounds__(1024, 4) void k3_seq(
    const float* __restrict__ stat, const float* __restrict__ dec_inp,
    const float* __restrict__ Whh, const float* __restrict__ bhh_g,
    const float* __restrict__ aW, const float* __restrict__ av,
    const float* __restrict__ pv, const float* __restrict__ wsf,
    int allow_general, float* __restrict__ out) {
    const int b = blockIdx.x;
    const int tid = threadIdx.x;

    __shared__ float sh_whh[LC][256];           // 128 KB weight cache
    __shared__ float sh_gh[768], sh_hv[256], sh_t1[256], sh_a[128];
    __shared__ float sh_sp0[128], sh_sp1[128], sh_lm[128];
    __shared__ float4 qa1[64], qa2[64], qva[64];   // attn logits quad operands
    __shared__ float4 qp1[64], qp2[64], qvp[64];   // ptr  logits quad operands
    __shared__ float sh_M3p[512];
    __shared__ float sh_ca[256], sh_cp[256], sh_cp3[256];
    __shared__ float sh_G[1536], sh_g0[768], sh_bhh[768];
    __shared__ float sh_scal[4];
    __shared__ int ycnt;

    const float* G_   = wsf + OFF_G;   const float* g0_  = wsf + OFF_G0;
    const float* M1a_ = wsf + OFF_M1A; const float* ca_  = wsf + OFF_CA;
    const float* M1p_ = wsf + OFF_M1P; const float* cp_  = wsf + OFF_CP;
    const float* M3p_ = wsf + OFF_M3P; const float* cp3_ = wsf + OFF_CP3;
    const float* lm_  = wsf + OFF_LM;
    const float* basea = wsf + OFF_BASEA;
    const float* basep = wsf + OFF_BASEP;
    const int* flag = (const int*)wsf;

    // W_hh rows 0..LC-1 into LDS (float4 cooperative copy, once)
    {
        float4* dst = (float4*)&sh_whh[0][0];
        const float4* src = (const float4*)Whh;
        for (int i = tid; i < LC * 64; i += 1024) dst[i] = src[i];
    }
    for (int i = tid; i < 1536; i += 1024) sh_G[i] = G_[i];
    for (int i = tid; i < 768; i += 1024) {
        sh_g0[i] = g0_[i];
        float bv = bhh_g[i];
        sh_bhh[i] = bv;
        sh_gh[i] = bv;            // gh for step 0: h0 = 0 => gh = b_hh
    }
    for (int i = tid; i < 512; i += 1024) sh_M3p[i] = M3p_[i];
    for (int i = tid; i < 256; i += 1024) {
        sh_ca[i] = ca_[i]; sh_cp[i] = cp_[i]; sh_cp3[i] = cp3_[i];
        sh_hv[i] = 0.f;
    }
    for (int i = tid; i < 128; i += 1024) {
        sh_sp0[i] = stat[((size_t)b * 3 + 1) * SS + i];
        sh_sp1[i] = stat[((size_t)b * 3 + 2) * SS + i];
        sh_lm[i]  = lm_[b * SS + i];
    }
    // quad-pack logit operands (step-invariant): 4 i per float4
    if (tid < 64) {
        int q = tid;
        qa1[q] = make_float4(M1a_[(4*q+0)*2], M1a_[(4*q+1)*2], M1a_[(4*q+2)*2], M1a_[(4*q+3)*2]);
        qa2[q] = make_float4(M1a_[(4*q+0)*2+1], M1a_[(4*q+1)*2+1], M1a_[(4*q+2)*2+1], M1a_[(4*q+3)*2+1]);
        qva[q] = make_float4(av[4*q+0], av[4*q+1], av[4*q+2], av[4*q+3]);
    } else if (tid < 128) {
        int q = tid - 64;
        qp1[q] = make_float4(M1p_[(4*q+0)*2], M1p_[(4*q+1)*2], M1p_[(4*q+2)*2], M1p_[(4*q+3)*2]);
        qp2[q] = make_float4(M1p_[(4*q+0)*2+1], M1p_[(4*q+1)*2+1], M1p_[(4*q+2)*2+1], M1p_[(4*q+3)*2+1]);
        qvp[q] = make_float4(pv[4*q+0], pv[4*q+1], pv[4*q+2], pv[4*q+3]);
    }
    if (tid == 0) {
        sh_scal[0] = dec_inp[b * 2 + 0];
        sh_scal[1] = dec_inp[b * 2 + 1];
        ycnt = 0;
    }
    const bool dz = (!allow_general) || (*flag == 0);
    __syncthreads();

    for (int t = 0; t < SS; ++t) {
        // ---- GRU gates (threads 0..255): h(t) from sh_gh + rank-2 gi fold
        if (tid < 256) {
            int k = tid;
            float d0 = sh_scal[0], d1 = sh_scal[1];
            float gr = fmaf(sh_G[k * 2],          d0, fmaf(sh_G[k * 2 + 1],          d1, sh_g0[k]));
            float gz = fmaf(sh_G[(k + 256) * 2],  d0, fmaf(sh_G[(k + 256) * 2 + 1],  d1, sh_g0[k + 256]));
            float gn = fmaf(sh_G[(k + 512) * 2],  d0, fmaf(sh_G[(k + 512) * 2 + 1],  d1, sh_g0[k + 512]));
            float r = 1.f / (1.f + expf(-(gr + sh_gh[k])));
            float z = 1.f / (1.f + expf(-(gz + sh_gh[k + 256])));
            float n = tanhf(gn + r * sh_gh[k + 512]);
            sh_hv[k] = (1.f - z) * n + z * sh_hv[k];
        }
        __syncthreads();      // h(t) visible to X and Y

        if (tid < 512) {
            // ===== X: sh_gh <- W_hh * h(t) + b_hh (for step t+1) =====
            if (t + 1 < SS) {
                const int xg = tid >> 4, xj = tid & 15;   // 32 row-groups x 16 lanes
                float4 hx0 = ((const float4*)sh_hv)[xj];
                float4 hx1 = ((const float4*)sh_hv)[xj + 16];
                float4 hx2 = ((const float4*)sh_hv)[xj + 32];
                float4 hx3 = ((const float4*)sh_hv)[xj + 48];
                // rows 0..127 from LDS cache
                #pragma unroll
                for (int k = 0; k < 4; ++k) {
                    int r = xg + 32 * k;
                    const float4* Wr = (const float4*)&sh_whh[r][0];
                    float4 w0 = Wr[xj], w1 = Wr[xj + 16], w2 = Wr[xj + 32], w3 = Wr[xj + 48];
                    DOT16(w0, w1, w2, w3)
                    if (xj == 0) sh_gh[r] = acc + sh_bhh[r];
                }
                // rows 128..767: manual 4-deep ping-pong register pipeline
                {
#define XPTR(kk) ((const float4*)(Whh + (size_t)(xg + 32 * (kk)) * 256))
                    const float4 *pA = XPTR(4), *pB = XPTR(5), *pC = XPTR(6), *pD = XPTR(7);
                    float4 A0 = pA[xj], A1 = pA[xj+16], A2 = pA[xj+32], A3 = pA[xj+48];
                    float4 B0 = pB[xj], B1 = pB[xj+16], B2 = pB[xj+32], B3 = pB[xj+48];
                    float4 C0 = pC[xj], C1 = pC[xj+16], C2 = pC[xj+32], C3 = pC[xj+48];
                    float4 D0 = pD[xj], D1 = pD[xj+16], D2 = pD[xj+32], D3 = pD[xj+48];
                    #pragma unroll
                    for (int k = 4; k < 24; k += 4) {
                        {
                            DOT16(A0, A1, A2, A3)
                            if (xj == 0) { int r = xg + 32 * k; sh_gh[r] = acc + sh_bhh[r]; }
                            if (k + 4 < 24) { const float4* p = XPTR(k + 4);
                                A0 = p[xj]; A1 = p[xj+16]; A2 = p[xj+32]; A3 = p[xj+48]; }
                        }
                        {
                            DOT16(B0, B1, B2, B3)
                            if (xj == 0) { int r = xg + 32 * (k+1); sh_gh[r] = acc + sh_bhh[r]; }
                            if (k + 5 < 24) { const float4* p = XPTR(k + 5);
                                B0 = p[xj]; B1 = p[xj+16]; B2 = p[xj+32]; B3 = p[xj+48]; }
                        }
                        {
                            DOT16(C0, C1, C2, C3)
                            if (xj == 0) { int r = xg + 32 * (k+2); sh_gh[r] = acc + sh_bhh[r]; }
                            if (k + 6 < 24) { const float4* p = XPTR(k + 6);
                                C0 = p[xj]; C1 = p[xj+16]; C2 = p[xj+32]; C3 = p[xj+48]; }
                        }
                        {
                            DOT16(D0, D1, D2, D3)
                            if (xj == 0) { int r = xg + 32 * (k+3); sh_gh[r] = acc + sh_bhh[r]; }
                            if (k + 7 < 24) { const float4* p = XPTR(k + 7);
                                D0 = p[xj]; D1 = p[xj+16]; D2 = p[xj+32]; D3 = p[xj+48]; }
                        }
                    }
#undef XPTR
                }
            }
        } else {
            // ===== Y: t1 -> attn -> softmax -> ptr -> argmax =====
            const int yt = tid - 512;
            const int ybase = t * 25;

            // Y1: t1 = A3 * h — manual 4-deep pipeline (+ ca on zero path)
            {
                const int yq = yt >> 4, yj = yt & 15;   // 32 row-groups
                float4 hx0 = ((const float4*)sh_hv)[yj];
                float4 hx1 = ((const float4*)sh_hv)[yj + 16];
                float4 hx2 = ((const float4*)sh_hv)[yj + 32];
                float4 hx3 = ((const float4*)sh_hv)[yj + 48];
#define YPTR(kk) ((const float4*)(aW + (size_t)(yq + 32 * (kk)) * 768 + 512))
                const float4 *pA = YPTR(0), *pB = YPTR(1), *pC = YPTR(2), *pD = YPTR(3);
                float4 A0 = pA[yj], A1 = pA[yj+16], A2 = pA[yj+32], A3 = pA[yj+48];
                float4 B0 = pB[yj], B1 = pB[yj+16], B2 = pB[yj+32], B3 = pB[yj+48];
                float4 C0 = pC[yj], C1 = pC[yj+16], C2 = pC[yj+32], C3 = pC[yj+48];
                float4 D0 = pD[yj], D1 = pD[yj+16], D2 = pD[yj+32], D3 = pD[yj+48];
                #pragma unroll
                for (int k = 0; k < 8; k += 4) {
                    {
                        DOT16(A0, A1, A2, A3)
                        if (yj == 0) { int r = yq + 32 * k; sh_t1[r] = acc + (dz ? sh_ca[r] : 0.f); }
                        if (k + 4 < 8) { const float4* p = YPTR(k + 4);
                            A0 = p[yj]; A1 = p[yj+16]; A2 = p[yj+32]; A3 = p[yj+48]; }
                    }
                    {
                        DOT16(B0, B1, B2, B3)
                        if (yj == 0) { int r = yq + 32 * (k+1); sh_t1[r] = acc + (dz ? sh_ca[r] : 0.f); }
                        if (k + 5 < 8) { const float4* p = YPTR(k + 5);
                            B0 = p[yj]; B1 = p[yj+16]; B2 = p[yj+32]; B3 = p[yj+48]; }
                    }
                    {
                        DOT16(C0, C1, C2, C3)
                        if (yj == 0) { int r = yq + 32 * (k+2); sh_t1[r] = acc + (dz ? sh_ca[r] : 0.f); }
                        if (k + 6 < 8) { const float4* p = YPTR(k + 6);
                            C0 = p[yj]; C1 = p[yj+16]; C2 = p[yj+32]; C3 = p[yj+48]; }
                    }
                    {
                        DOT16(D0, D1, D2, D3)
                        if (yj == 0) { int r = yq + 32 * (k+3); sh_t1[r] = acc + (dz ? sh_ca[r] : 0.f); }
                        if (k + 7 < 8) { const float4* p = YPTR(k + 7);
                            D0 = p[yj]; D1 = p[yj+16]; D2 = p[yj+32]; D3 = p[yj+48]; }
                    }
                }
#undef YPTR
            }
            ybar(&ycnt, true, ybase + 8);

            // Y2: attn logits (4 threads per s, quad-vectorized)
            {
                int s = yt >> 2, g = yt & 3;
                float acc = 0.f;
                if (dz) {
                    float s0 = sh_sp0[s], s1 = sh_sp1[s];
                    #pragma unroll 4
                    for (int q = g; q < 64; q += 4) {
                        float4 A1 = qa1[q], A2 = qa2[q], V = qva[q];
                        float4 T = ((const float4*)sh_t1)[q];
                        acc = fmaf(V.x, tanh_fast(fmaf(A1.x, s0, fmaf(A2.x, s1, T.x))), acc);
                        acc = fmaf(V.y, tanh_fast(fmaf(A1.y, s0, fmaf(A2.y, s1, T.y))), acc);
                        acc = fmaf(V.z, tanh_fast(fmaf(A1.z, s0, fmaf(A2.z, s1, T.z))), acc);
                        acc = fmaf(V.w, tanh_fast(fmaf(A1.w, s0, fmaf(A2.w, s1, T.w))), acc);
                    }
                } else {
                    const float* bb = basea + ((size_t)b * SS + s) * HH;
                    #pragma unroll 4
                    for (int q = g; q < 64; q += 4) {
                        float4 V = qva[q];
                        float4 T = ((const float4*)sh_t1)[q];
                        float4 B = *(const float4*)(bb + q * 4);
                        acc = fmaf(V.x, tanh_fast(B.x + T.x), acc);
                        acc = fmaf(V.y, tanh_fast(B.y + T.y), acc);
                        acc = fmaf(V.z, tanh_fast(B.z + T.z), acc);
                        acc = fmaf(V.w, tanh_fast(B.w + T.w), acc);
                    }
                }
                acc += __shfl_xor(acc, 1, 4); acc += __shfl_xor(acc, 2, 4);
                if (g == 0) sh_a[s] = acc;
            }
            ybar(&ycnt, true, ybase + 16);

            // Y3: softmax + context + t2 fold (wave 8 only)
            if (yt < 64) {
                int ln = yt;
                float v0 = sh_a[ln], v1 = sh_a[ln + 64];
                float m = fmaxf(v0, v1);
                for (int msk = 1; msk < 64; msk <<= 1) m = fmaxf(m, __shfl_xor(m, msk, 64));
                float e0 = expf(v0 - m), e1 = expf(v1 - m);
                float S = e0 + e1;
                float c0 = e0 * sh_sp0[ln] + e1 * sh_sp0[ln + 64];
                float c1 = e0 * sh_sp1[ln] + e1 * sh_sp1[ln + 64];
                for (int msk = 1; msk < 64; msk <<= 1) {
                    S  += __shfl_xor(S,  msk, 64);
                    c0 += __shfl_xor(c0, msk, 64);
                    c1 += __shfl_xor(c1, msk, 64);
                }
                float C0 = c0 / S, C1 = c1 / S;
                #pragma unroll
                for (int q = 0; q < 4; ++q) {
                    int k2 = ln + 64 * q;
                    float v = fmaf(sh_M3p[k2 * 2], C0, fmaf(sh_M3p[k2 * 2 + 1], C1, sh_cp3[k2]));
                    sh_t1[k2] = v + (dz ? sh_cp[k2] : 0.f);
                }
                ybar(&ycnt, true, ybase + 17);
            } else {
                ybar(&ycnt, false, ybase + 17);
            }

            // Y4: ptr logits (quad-vectorized)
            {
                int s = yt >> 2, g = yt & 3;
                float acc = 0.f;
                if (dz) {
                    float s0 = sh_sp0[s], s1 = sh_sp1[s];
                    #pragma unroll 4
                    for (int q = g; q < 64; q += 4) {
                        float4 A1 = qp1[q], A2 = qp2[q], V = qvp[q];
                        float4 T = ((const float4*)sh_t1)[q];
                        acc = fmaf(V.x, tanh_fast(fmaf(A1.x, s0, fmaf(A2.x, s1, T.x))), acc);
                        acc = fmaf(V.y, tanh_fast(fmaf(A1.y, s0, fmaf(A2.y, s1, T.y))), acc);
                        acc = fmaf(V.z, tanh_fast(fmaf(A1.z, s0, fmaf(A2.z, s1, T.z))), acc);
                        acc = fmaf(V.w, tanh_fast(fmaf(A1.w, s0, fmaf(A2.w, s1, T.w))), acc);
                    }
                } else {
                    const float* bb = basep + ((size_t)b * SS + s) * HH;
                    #pragma unroll 4
                    for (int q = g; q < 64; q += 4) {
                        float4 V = qvp[q];
                        float4 T = ((const float4*)sh_t1)[q];
                        float4 B = *(const float4*)(bb + q * 4);
                        acc = fmaf(V.x, tanh_fast(B.x + T.x), acc);
                        acc = fmaf(V.y, tanh_fast(B.y + T.y), acc);
                        acc = fmaf(V.z, tanh_fast(B.z + T.z), acc);
                        acc = fmaf(V.w, tanh_fast(B.w + T.w), acc);
                    }
                }
                acc += __shfl_xor(acc, 1, 4); acc += __shfl_xor(acc, 2, 4);
                if (g == 0) sh_a[s] = acc;
            }
            ybar(&ycnt, true, ybase + 25);

            // Y5: masked argmax + logp + dec_in update (wave 8 only)
            if (yt < 64) {
                int ln = yt;
                float l0 = sh_a[ln] + sh_lm[ln];
                float l1 = sh_a[ln + 64] + sh_lm[ln + 64];
                float v; int idx;
                if (l0 >= l1) { v = l0; idx = ln; } else { v = l1; idx = ln + 64; }
                for (int msk = 1; msk < 64; msk <<= 1) {
                    float ov = __shfl_xor(v, msk, 64);
                    int   oi = __shfl_xor(idx, msk, 64);
                    if (ov > v || (ov == v && oi < idx)) { v = ov; idx = oi; }
                }
                float S = expf(l0 - v) + expf(l1 - v);
                for (int msk = 1; msk < 64; msk <<= 1) S += __shfl_xor(S, msk, 64);
                if (ln == 0) {
                    out[b * SS + t] = (float)idx;
                    out[BB * SS + b * SS + t] = -logf(S);
                    sh_scal[0] = sh_sp0[idx];
                    sh_scal[1] = sh_sp1[idx];
                }
            }
        }
        __syncthreads();      // gh(t+1), dec_in, Y buffers all settled
    }
}

extern "C" void kernel_launch(void* const* d_in, const int* in_sizes, int n_in,
                              void* d_out, int out_size, void* d_ws, size_t ws_size,
                              hipStream_t stream) {
    const float* stat  = (const float*)d_in[0];
    const float* dyn   = (const float*)d_in[1];
    const float* decin = (const float*)d_in[2];
    const float* esW   = (const float*)d_in[3];
    const float* esb   = (const float*)d_in[4];
    const float* edW   = (const float*)d_in[5];
    const float* edb   = (const float*)d_in[6];
    const float* dW    = (const float*)d_in[7];
    const float* db    = (const float*)d_in[8];
    const float* Wih   = (const float*)d_in[9];
    const float* Whh   = (const float*)d_in[10];
    const float* bih   = (const float*)d_in[11];
    const float* bhh   = (const float*)d_in[12];
    const float* av    = (const float*)d_in[13];
    const float* aW    = (const float*)d_in[14];
    const float* pv    = (const float*)d_in[15];
    const float* pW    = (const float*)d_in[16];
    float* wsf = (float*)d_ws;
    int* flag  = (int*)d_ws;
    float* out = (float*)d_out;

    int allow_general = (ws_size >= (size_t)OFF_END * 4) ? 1 : 0;

    hipMemsetAsync(d_ws, 0, 256, stream);
    hipLaunchKernelGGL(k1_logmask, dim3(64), dim3(256), 0, stream, dyn, wsf + OFF_LM, flag);
    hipLaunchKernelGGL(k0a_folds, dim3(18), dim3(256), 0, stream,
                       Wih, bih, dW, db, aW, pW, esW, esb, edb, wsf);
    if (allow_general) {
        hipLaunchKernelGGL(k0b_m2, dim3(384), dim3(256), 0, stream, aW, pW, edW, wsf, flag);
        hipLaunchKernelGGL(k2_bases, dim3(256), dim3(256), 0, stream, stat, dyn, wsf, flag);
    }
    hipLaunchKernelGGL(k3_seq, dim3(128), dim3(1024), 0, stream,
                       stat, decin, Whh, bhh, aW, av, pv, wsf, allow_general, out);
}

// Round 14
// 1768.896 us; speedup vs baseline: 2.3671x; 2.3671x over previous
//
#include <hip/hip_runtime.h>
#include <hip/hip_bf16.h>
#include <math.h>

// Problem dims
#define BB   128   // batch
#define SS   128   // sequence / positions
#define HH   256   // hidden
#define DYNN 192   // dynamic channels
#define LC   128   // W_hh rows cached in LDS (rows 0..LC-1)

// ws layout (float offsets)
#define OFF_FLAG  0
#define OFF_G     64
#define OFF_G0    (OFF_G + 1536)
#define OFF_M1A   (OFF_G0 + 768)
#define OFF_CA    (OFF_M1A + 512)
#define OFF_M1P   (OFF_CA + 256)
#define OFF_CP    (OFF_M1P + 512)
#define OFF_M3P   (OFF_CP + 256)
#define OFF_CP3   (OFF_M3P + 512)
#define OFF_LM    (OFF_CP3 + 256)
#define OFF_M2A   (OFF_LM + 16384)
#define OFF_M2P   (OFF_M2A + 49152)
#define OFF_BASEA (OFF_M2P + 49152)
#define OFF_BASEP (OFF_BASEA + 4194304)
#define OFF_END   (OFF_BASEP + 4194304)

__device__ __forceinline__ float tanh_fast(float x) {
    float e = __builtin_amdgcn_exp2f(x * 2.885390081777927f); // 2*log2(e)
    return 1.0f - 2.0f * __builtin_amdgcn_rcpf(e + 1.0f);
}

// Y-group spin barrier: monotone LDS counter, wave leaders add 1. (proven R3/R5/R6)
__device__ __forceinline__ void ybar(int* cnt, bool arrive, int target) {
    if (arrive && (threadIdx.x & 63) == 0)
        __hip_atomic_fetch_add(cnt, 1, __ATOMIC_RELEASE, __HIP_MEMORY_SCOPE_WORKGROUP);
    while (__hip_atomic_load(cnt, __ATOMIC_ACQUIRE, __HIP_MEMORY_SCOPE_WORKGROUP) < target)
        __builtin_amdgcn_s_sleep(1);
}

// K1: logmask + "dynamic is nonzero" flag
__global__ void k1_logmask(const float* __restrict__ dyn, float* __restrict__ lm,
                           int* __restrict__ flag) {
    int g = blockIdx.x * 256 + threadIdx.x;
    if (g >= BB * SS) return;
    int b = g >> 7, s = g & 127;
    const float* p = dyn + (size_t)b * DYNN * SS + s;
    float mv = 0.f, m1 = 0.f, m2 = 0.f;
    bool nz = false;
    for (int i = 0; i < 64; ++i)        { float v = p[(size_t)i * SS]; mv += v; nz |= (v != 0.f); }
    for (int i = 64; i < 128; ++i)      { float v = p[(size_t)i * SS]; m1 += v; nz |= (v != 0.f); }
    for (int i = 128; i < 192; ++i)     { float v = p[(size_t)i * SS]; m2 += v; nz |= (v != 0.f); }
    float dm = m1 * m2 + mv;
    lm[g] = (dm != 0.f) ? -__builtin_inff() : 0.f;
    if (nz) atomicOr(flag, 1);
}

// K0a: small weight folds (rank-2 eliminations)
__global__ void k0a_folds(const float* __restrict__ Wih, const float* __restrict__ bih,
                          const float* __restrict__ dW,  const float* __restrict__ db,
                          const float* __restrict__ aW,  const float* __restrict__ pW,
                          const float* __restrict__ esW, const float* __restrict__ esb,
                          const float* __restrict__ edb, float* __restrict__ wsf) {
    int idx = blockIdx.x * 256 + threadIdx.x;
    float* G   = wsf + OFF_G;
    float* g0  = wsf + OFF_G0;
    float* M1a = wsf + OFF_M1A;
    float* ca  = wsf + OFF_CA;
    float* M1p = wsf + OFF_M1P;
    float* cp  = wsf + OFF_CP;
    float* M3p = wsf + OFF_M3P;
    float* cp3 = wsf + OFF_CP3;
    if (idx < 1536) {
        int r = idx >> 1, j = idx & 1;
        float a = 0.f;
        for (int k = 0; k < 256; ++k) a += Wih[r * 256 + k] * dW[k * 2 + j];
        G[idx] = a;
    } else if (idx < 2304) {
        int r = idx - 1536;
        float a = 0.f;
        for (int k = 0; k < 256; ++k) a += Wih[r * 256 + k] * db[k];
        g0[r] = a + bih[r];
    } else if (idx < 2816) {
        int t = idx - 2304; int h = t >> 1, j = t & 1;
        float a = 0.f;
        for (int k = 0; k < 256; ++k) a += aW[h * 768 + k] * esW[k * 2 + j];
        M1a[t] = a;
    } else if (idx < 3072) {
        int h = idx - 2816;
        float a = 0.f, b2 = 0.f;
        for (int k = 0; k < 256; ++k) a  += aW[h * 768 + k]       * esb[k];
        for (int k = 0; k < 256; ++k) b2 += aW[h * 768 + 256 + k] * edb[k];
        ca[h] = a + b2;
    } else if (idx < 3584) {
        int t = idx - 3072; int h = t >> 1, j = t & 1;
        float a = 0.f;
        for (int k = 0; k < 256; ++k) a += pW[h * 768 + k] * esW[k * 2 + j];
        M1p[t] = a;
    } else if (idx < 3840) {
        int h = idx - 3584;
        float a = 0.f, b2 = 0.f;
        for (int k = 0; k < 256; ++k) a  += pW[h * 768 + k]       * esb[k];
        for (int k = 0; k < 256; ++k) b2 += pW[h * 768 + 256 + k] * edb[k];
        cp[h] = a + b2;
    } else if (idx < 4352) {
        int t = idx - 3840; int h = t >> 1, j = t & 1;
        float a = 0.f;
        for (int k = 0; k < 256; ++k) a += pW[h * 768 + 512 + k] * esW[k * 2 + j];
        M3p[t] = a;
    } else if (idx < 4608) {
        int h = idx - 4352;
        float a = 0.f;
        for (int k = 0; k < 256; ++k) a += pW[h * 768 + 512 + k] * esb[k];
        cp3[h] = a;
    }
}

// K0b: M2a/M2p folds for the general (dynamic != 0) path
__global__ void k0b_m2(const float* __restrict__ aW, const float* __restrict__ pW,
                       const float* __restrict__ edW, float* __restrict__ wsf,
                       const int* __restrict__ flag) {
    if (*flag == 0) return;
    int idx = blockIdx.x * 256 + threadIdx.x;
    if (idx >= 2 * 49152) return;
    int which = idx / 49152;
    int t = idx % 49152;
    int h = t / DYNN, i = t % DYNN;
    const float* W = which ? pW : aW;
    float a = 0.f;
    for (int k = 0; k < 256; ++k) a += W[h * 768 + 256 + k] * edW[k * DYNN + i];
    wsf[(which ? OFF_M2P : OFF_M2A) + t] = a;
}

// K2: general-path bases, layout [b][s][h]
__global__ void k2_bases(const float* __restrict__ stat, const float* __restrict__ dyn,
                         float* __restrict__ wsf, const int* __restrict__ flag) {
    if (*flag == 0) return;
    __shared__ float col[DYNN];
    __shared__ float s01[2];
    const float* M1a = wsf + OFF_M1A; const float* ca  = wsf + OFF_CA;
    const float* M1p = wsf + OFF_M1P; const float* cp  = wsf + OFF_CP;
    const float* M2a = wsf + OFF_M2A; const float* M2p = wsf + OFF_M2P;
    float* basea = wsf + OFF_BASEA;   float* basep = wsf + OFF_BASEP;
    for (int pair = blockIdx.x; pair < BB * SS; pair += gridDim.x) {
        int b = pair >> 7, s = pair & 127;
        if (threadIdx.x < DYNN) col[threadIdx.x] = dyn[((size_t)b * DYNN + threadIdx.x) * SS + s];
        if (threadIdx.x == DYNN) {
            s01[0] = stat[((size_t)b * 3 + 1) * SS + s];
            s01[1] = stat[((size_t)b * 3 + 2) * SS + s];
        }
        __syncthreads();
        int h = threadIdx.x;
        float aa = fmaf(M1a[h * 2], s01[0], fmaf(M1a[h * 2 + 1], s01[1], ca[h]));
        float pp = fmaf(M1p[h * 2], s01[0], fmaf(M1p[h * 2 + 1], s01[1], cp[h]));
        for (int i = 0; i < DYNN; ++i) {
            aa = fmaf(M2a[h * DYNN + i], col[i], aa);
            pp = fmaf(M2p[h * DYNN + i], col[i], pp);
        }
        basea[((size_t)b * SS + s) * HH + h] = aa;
        basep[((size_t)b * SS + s) * HH + h] = pp;
        __syncthreads();
    }
}

// Row dot-product: fmaf nest + width-16 reduce, bitwise identical across rounds.
#define DOT16(W0, W1, W2, W3)                                                                    \
    float acc = 0.f;                                                                             \
    acc = fmaf(W0.x, hx0.x, fmaf(W0.y, hx0.y, fmaf(W0.z, hx0.z, fmaf(W0.w, hx0.w, acc))));       \
    acc = fmaf(W1.x, hx1.x, fmaf(W1.y, hx1.y, fmaf(W1.z, hx1.z, fmaf(W1.w, hx1.w, acc))));       \
    acc = fmaf(W2.x, hx2.x, fmaf(W2.y, hx2.y, fmaf(W2.z, hx2.z, fmaf(W2.w, hx2.w, acc))));       \
    acc = fmaf(W3.x, hx3.x, fmaf(W3.y, hx3.y, fmaf(W3.z, hx3.z, fmaf(W3.w, hx3.w, acc))));       \
    acc += __shfl_xor(acc, 1, 16); acc += __shfl_xor(acc, 2, 16);                                \
    acc += __shfl_xor(acc, 4, 16); acc += __shfl_xor(acc, 8, 16);

// K3: sequential decoder, one WG per batch (grid=128, 1024 threads).
//   waves 0-7  (X): gh(t+1) rows 0..127 (LDS cache) + rows 128..639 (L2 stream).
//   waves 8-15 (Y): t1=A3*h -> attn -> softmax -> ptr -> argmax, THEN help X
//     with gh rows 640..767 (needs only sh_hv; no new barriers).
// R14 = R11 (best, 1621us) + work-shift: Y's post-argmax idle tail absorbs
// 128 KB of the X stream (X was the critical path; streams run at the fixed
// ~71 GB/s/CU combined rate, so shifting bytes to idle waves shortens the step).
__global__ __launch_bounds__(1024) void k3_seq(
    const float* __restrict__ stat, const float* __restrict__ dec_inp,
    const float* __restrict__ Whh, const float* __restrict__ bhh_g,
    const float* __restrict__ aW, const float* __restrict__ av,
    const float* __restrict__ pv, const float* __restrict__ wsf,
    int allow_general, float* __restrict__ out) {
    const int b = blockIdx.x;
    const int tid = threadIdx.x;

    __shared__ float sh_whh[LC][256];           // 128 KB weight cache
    __shared__ float sh_gh[768], sh_hv[256], sh_t1[256], sh_a[128];
    __shared__ float sh_sp0[128], sh_sp1[128], sh_lm[128];
    __shared__ float4 qa1[64], qa2[64], qva[64];   // attn logits quad operands
    __shared__ float4 qp1[64], qp2[64], qvp[64];   // ptr  logits quad operands
    __shared__ float sh_M3p[512];
    __shared__ float sh_ca[256], sh_cp[256], sh_cp3[256];
    __shared__ float sh_G[1536], sh_g0[768], sh_bhh[768];
    __shared__ float sh_scal[4];
    __shared__ int ycnt;

    const float* G_   = wsf + OFF_G;   const float* g0_  = wsf + OFF_G0;
    const float* M1a_ = wsf + OFF_M1A; const float* ca_  = wsf + OFF_CA;
    const float* M1p_ = wsf + OFF_M1P; const float* cp_  = wsf + OFF_CP;
    const float* M3p_ = wsf + OFF_M3P; const float* cp3_ = wsf + OFF_CP3;
    const float* lm_  = wsf + OFF_LM;
    const float* basea = wsf + OFF_BASEA;
    const float* basep = wsf + OFF_BASEP;
    const int* flag = (const int*)wsf;

    // W_hh rows 0..LC-1 into LDS (float4 cooperative copy, once)
    {
        float4* dst = (float4*)&sh_whh[0][0];
        const float4* src = (const float4*)Whh;
        for (int i = tid; i < LC * 64; i += 1024) dst[i] = src[i];
    }
    for (int i = tid; i < 1536; i += 1024) sh_G[i] = G_[i];
    for (int i = tid; i < 768; i += 1024) {
        sh_g0[i] = g0_[i];
        float bv = bhh_g[i];
        sh_bhh[i] = bv;
        sh_gh[i] = bv;            // gh for step 0: h0 = 0 => gh = b_hh
    }
    for (int i = tid; i < 512; i += 1024) sh_M3p[i] = M3p_[i];
    for (int i = tid; i < 256; i += 1024) {
        sh_ca[i] = ca_[i]; sh_cp[i] = cp_[i]; sh_cp3[i] = cp3_[i];
        sh_hv[i] = 0.f;
    }
    for (int i = tid; i < 128; i += 1024) {
        sh_sp0[i] = stat[((size_t)b * 3 + 1) * SS + i];
        sh_sp1[i] = stat[((size_t)b * 3 + 2) * SS + i];
        sh_lm[i]  = lm_[b * SS + i];
    }
    // quad-pack logit operands (step-invariant): 4 i per float4
    if (tid < 64) {
        int q = tid;
        qa1[q] = make_float4(M1a_[(4*q+0)*2], M1a_[(4*q+1)*2], M1a_[(4*q+2)*2], M1a_[(4*q+3)*2]);
        qa2[q] = make_float4(M1a_[(4*q+0)*2+1], M1a_[(4*q+1)*2+1], M1a_[(4*q+2)*2+1], M1a_[(4*q+3)*2+1]);
        qva[q] = make_float4(av[4*q+0], av[4*q+1], av[4*q+2], av[4*q+3]);
    } else if (tid < 128) {
        int q = tid - 64;
        qp1[q] = make_float4(M1p_[(4*q+0)*2], M1p_[(4*q+1)*2], M1p_[(4*q+2)*2], M1p_[(4*q+3)*2]);
        qp2[q] = make_float4(M1p_[(4*q+0)*2+1], M1p_[(4*q+1)*2+1], M1p_[(4*q+2)*2+1], M1p_[(4*q+3)*2+1]);
        qvp[q] = make_float4(pv[4*q+0], pv[4*q+1], pv[4*q+2], pv[4*q+3]);
    }
    if (tid == 0) {
        sh_scal[0] = dec_inp[b * 2 + 0];
        sh_scal[1] = dec_inp[b * 2 + 1];
        ycnt = 0;
    }
    const bool dz = (!allow_general) || (*flag == 0);
    __syncthreads();

    for (int t = 0; t < SS; ++t) {
        // ---- GRU gates (threads 0..255): h(t) from sh_gh + rank-2 gi fold
        if (tid < 256) {
            int k = tid;
            float d0 = sh_scal[0], d1 = sh_scal[1];
            float gr = fmaf(sh_G[k * 2],          d0, fmaf(sh_G[k * 2 + 1],          d1, sh_g0[k]));
            float gz = fmaf(sh_G[(k + 256) * 2],  d0, fmaf(sh_G[(k + 256) * 2 + 1],  d1, sh_g0[k + 256]));
            float gn = fmaf(sh_G[(k + 512) * 2],  d0, fmaf(sh_G[(k + 512) * 2 + 1],  d1, sh_g0[k + 512]));
            float r = 1.f / (1.f + expf(-(gr + sh_gh[k])));
            float z = 1.f / (1.f + expf(-(gz + sh_gh[k + 256])));
            float n = tanhf(gn + r * sh_gh[k + 512]);
            sh_hv[k] = (1.f - z) * n + z * sh_hv[k];
        }
        __syncthreads();      // h(t) visible to X and Y

        if (tid < 512) {
            // ===== X: gh rows 0..639 (LDS-cached 0..127, streamed 128..639) =====
            if (t + 1 < SS) {
                const int xg = tid >> 4, xj = tid & 15;   // 32 row-groups x 16 lanes
                float4 hx0 = ((const float4*)sh_hv)[xj];
                float4 hx1 = ((const float4*)sh_hv)[xj + 16];
                float4 hx2 = ((const float4*)sh_hv)[xj + 32];
                float4 hx3 = ((const float4*)sh_hv)[xj + 48];
                // rows 0..127 from LDS cache
                #pragma unroll
                for (int k = 0; k < 4; ++k) {
                    int r = xg + 32 * k;
                    const float4* Wr = (const float4*)&sh_whh[r][0];
                    float4 w0 = Wr[xj], w1 = Wr[xj + 16], w2 = Wr[xj + 32], w3 = Wr[xj + 48];
                    DOT16(w0, w1, w2, w3)
                    if (xj == 0) sh_gh[r] = acc + sh_bhh[r];
                }
                // rows 128..639 streamed from L2
                #pragma unroll 2
                for (int k = 4; k < 20; ++k) {
                    int r = xg + 32 * k;
                    const float4* Wr = (const float4*)(Whh + (size_t)r * 256);
                    float4 w0 = Wr[xj], w1 = Wr[xj + 16], w2 = Wr[xj + 32], w3 = Wr[xj + 48];
                    DOT16(w0, w1, w2, w3)
                    if (xj == 0) sh_gh[r] = acc + sh_bhh[r];
                }
            }
        } else {
            // ===== Y: t1 -> attn -> softmax -> ptr -> argmax -> gh-help =====
            const int yt = tid - 512;
            const int ybase = t * 25;

            // Y1: t1 = A3 * h (stream A3 from L2) (+ ca on zero path)
            {
                const int yq = yt >> 4, yj = yt & 15;   // 32 row-groups
                float4 hx0 = ((const float4*)sh_hv)[yj];
                float4 hx1 = ((const float4*)sh_hv)[yj + 16];
                float4 hx2 = ((const float4*)sh_hv)[yj + 32];
                float4 hx3 = ((const float4*)sh_hv)[yj + 48];
                #pragma unroll 2
                for (int k = 0; k < 8; ++k) {
                    int r = yq + 32 * k;
                    const float4* Wr = (const float4*)(aW + (size_t)r * 768 + 512);
                    float4 w0 = Wr[yj], w1 = Wr[yj + 16], w2 = Wr[yj + 32], w3 = Wr[yj + 48];
                    DOT16(w0, w1, w2, w3)
                    if (yj == 0) sh_t1[r] = acc + (dz ? sh_ca[r] : 0.f);
                }
            }
            ybar(&ycnt, true, ybase + 8);

            // Y2: attn logits (4 threads per s, quad-vectorized)
            {
                int s = yt >> 2, g = yt & 3;
                float acc = 0.f;
                if (dz) {
                    float s0 = sh_sp0[s], s1 = sh_sp1[s];
                    #pragma unroll 4
                    for (int q = g; q < 64; q += 4) {
                        float4 A1 = qa1[q], A2 = qa2[q], V = qva[q];
                        float4 T = ((const float4*)sh_t1)[q];
                        acc = fmaf(V.x, tanh_fast(fmaf(A1.x, s0, fmaf(A2.x, s1, T.x))), acc);
                        acc = fmaf(V.y, tanh_fast(fmaf(A1.y, s0, fmaf(A2.y, s1, T.y))), acc);
                        acc = fmaf(V.z, tanh_fast(fmaf(A1.z, s0, fmaf(A2.z, s1, T.z))), acc);
                        acc = fmaf(V.w, tanh_fast(fmaf(A1.w, s0, fmaf(A2.w, s1, T.w))), acc);
                    }
                } else {
                    const float* bb = basea + ((size_t)b * SS + s) * HH;
                    #pragma unroll 4
                    for (int q = g; q < 64; q += 4) {
                        float4 V = qva[q];
                        float4 T = ((const float4*)sh_t1)[q];
                        float4 B = *(const float4*)(bb + q * 4);
                        acc = fmaf(V.x, tanh_fast(B.x + T.x), acc);
                        acc = fmaf(V.y, tanh_fast(B.y + T.y), acc);
                        acc = fmaf(V.z, tanh_fast(B.z + T.z), acc);
                        acc = fmaf(V.w, tanh_fast(B.w + T.w), acc);
                    }
                }
                acc += __shfl_xor(acc, 1, 4); acc += __shfl_xor(acc, 2, 4);
                if (g == 0) sh_a[s] = acc;
            }
            ybar(&ycnt, true, ybase + 16);

            // Y3: softmax + context + t2 fold (wave 8 only)
            if (yt < 64) {
                int ln = yt;
                float v0 = sh_a[ln], v1 = sh_a[ln + 64];
                float m = fmaxf(v0, v1);
                for (int msk = 1; msk < 64; msk <<= 1) m = fmaxf(m, __shfl_xor(m, msk, 64));
                float e0 = expf(v0 - m), e1 = expf(v1 - m);
                float S = e0 + e1;
                float c0 = e0 * sh_sp0[ln] + e1 * sh_sp0[ln + 64];
                float c1 = e0 * sh_sp1[ln] + e1 * sh_sp1[ln + 64];
                for (int msk = 1; msk < 64; msk <<= 1) {
                    S  += __shfl_xor(S,  msk, 64);
                    c0 += __shfl_xor(c0, msk, 64);
                    c1 += __shfl_xor(c1, msk, 64);
                }
                float C0 = c0 / S, C1 = c1 / S;
                #pragma unroll
                for (int q = 0; q < 4; ++q) {
                    int k2 = ln + 64 * q;
                    float v = fmaf(sh_M3p[k2 * 2], C0, fmaf(sh_M3p[k2 * 2 + 1], C1, sh_cp3[k2]));
                    sh_t1[k2] = v + (dz ? sh_cp[k2] : 0.f);
                }
                ybar(&ycnt, true, ybase + 17);
            } else {
                ybar(&ycnt, false, ybase + 17);
            }

            // Y4: ptr logits (quad-vectorized)
            {
                int s = yt >> 2, g = yt & 3;
                float acc = 0.f;
                if (dz) {
                    float s0 = sh_sp0[s], s1 = sh_sp1[s];
                    #pragma unroll 4
                    for (int q = g; q < 64; q += 4) {
                        float4 A1 = qp1[q], A2 = qp2[q], V = qvp[q];
                        float4 T = ((const float4*)sh_t1)[q];
                        acc = fmaf(V.x, tanh_fast(fmaf(A1.x, s0, fmaf(A2.x, s1, T.x))), acc);
                        acc = fmaf(V.y, tanh_fast(fmaf(A1.y, s0, fmaf(A2.y, s1, T.y))), acc);
                        acc = fmaf(V.z, tanh_fast(fmaf(A1.z, s0, fmaf(A2.z, s1, T.z))), acc);
                        acc = fmaf(V.w, tanh_fast(fmaf(A1.w, s0, fmaf(A2.w, s1, T.w))), acc);
                    }
                } else {
                    const float* bb = basep + ((size_t)b * SS + s) * HH;
                    #pragma unroll 4
                    for (int q = g; q < 64; q += 4) {
                        float4 V = qvp[q];
                        float4 T = ((const float4*)sh_t1)[q];
                        float4 B = *(const float4*)(bb + q * 4);
                        acc = fmaf(V.x, tanh_fast(B.x + T.x), acc);
                        acc = fmaf(V.y, tanh_fast(B.y + T.y), acc);
                        acc = fmaf(V.z, tanh_fast(B.z + T.z), acc);
                        acc = fmaf(V.w, tanh_fast(B.w + T.w), acc);
                    }
                }
                acc += __shfl_xor(acc, 1, 4); acc += __shfl_xor(acc, 2, 4);
                if (g == 0) sh_a[s] = acc;
            }
            ybar(&ycnt, true, ybase + 25);

            // Y5: masked argmax + logp + dec_in update (wave 8 only)
            if (yt < 64) {
                int ln = yt;
                float l0 = sh_a[ln] + sh_lm[ln];
                float l1 = sh_a[ln + 64] + sh_lm[ln + 64];
                float v; int idx;
                if (l0 >= l1) { v = l0; idx = ln; } else { v = l1; idx = ln + 64; }
                for (int msk = 1; msk < 64; msk <<= 1) {
                    float ov = __shfl_xor(v, msk, 64);
                    int   oi = __shfl_xor(idx, msk, 64);
                    if (ov > v || (ov == v && oi < idx)) { v = ov; idx = oi; }
                }
                float S = expf(l0 - v) + expf(l1 - v);
                for (int msk = 1; msk < 64; msk <<= 1) S += __shfl_xor(S, msk, 64);
                if (ln == 0) {
                    out[b * SS + t] = (float)idx;
                    out[BB * SS + b * SS + t] = -logf(S);
                    sh_scal[0] = sh_sp0[idx];
                    sh_scal[1] = sh_sp1[idx];
                }
            }

            // Y6: help X — gh rows 640..767 (needs only sh_hv, written before
            // the end-of-step __syncthreads; identical DOT16 row arithmetic)
            if (t + 1 < SS) {
                const int yq = yt >> 4, yj = yt & 15;
                float4 hx0 = ((const float4*)sh_hv)[yj];
                float4 hx1 = ((const float4*)sh_hv)[yj + 16];
                float4 hx2 = ((const float4*)sh_hv)[yj + 32];
                float4 hx3 = ((const float4*)sh_hv)[yj + 48];
                #pragma unroll 2
                for (int k = 0; k < 4; ++k) {
                    int r = 640 + yq + 32 * k;
                    const float4* Wr = (const float4*)(Whh + (size_t)r * 256);
                    float4 w0 = Wr[yj], w1 = Wr[yj + 16], w2 = Wr[yj + 32], w3 = Wr[yj + 48];
                    DOT16(w0, w1, w2, w3)
                    if (yj == 0) sh_gh[r] = acc + sh_bhh[r];
                }
            }
        }
        __syncthreads();      // gh(t+1), dec_in, Y buffers all settled
    }
}

extern "C" void kernel_launch(void* const* d_in, const int* in_sizes, int n_in,
                              void* d_out, int out_size, void* d_ws, size_t ws_size,
                              hipStream_t stream) {
    const float* stat  = (const float*)d_in[0];
    const float* dyn   = (const float*)d_in[1];
    const float* decin = (const float*)d_in[2];
    const float* esW   = (const float*)d_in[3];
    const float* esb   = (const float*)d_in[4];
    const float* edW   = (const float*)d_in[5];
    const float* edb   = (const float*)d_in[6];
    const float* dW    = (const float*)d_in[7];
    const float* db    = (const float*)d_in[8];
    const float* Wih   = (const float*)d_in[9];
    const float* Whh   = (const float*)d_in[10];
    const float* bih   = (const float*)d_in[11];
    const float* bhh   = (const float*)d_in[12];
    const float* av    = (const float*)d_in[13];
    const float* aW    = (const float*)d_in[14];
    const float* pv    = (const float*)d_in[15];
    const float* pW    = (const float*)d_in[16];
    float* wsf = (float*)d_ws;
    int* flag  = (int*)d_ws;
    float* out = (float*)d_out;

    int allow_general = (ws_size >= (size_t)OFF_END * 4) ? 1 : 0;

    hipMemsetAsync(d_ws, 0, 256, stream);
    hipLaunchKernelGGL(k1_logmask, dim3(64), dim3(256), 0, stream, dyn, wsf + OFF_LM, flag);
    hipLaunchKernelGGL(k0a_folds, dim3(18), dim3(256), 0, stream,
                       Wih, bih, dW, db, aW, pW, esW, esb, edb, wsf);
    if (allow_general) {
        hipLaunchKernelGGL(k0b_m2, dim3(384), dim3(256), 0, stream, aW, pW, edW, wsf, flag);
        hipLaunchKernelGGL(k2_bases, dim3(256), dim3(256), 0, stream, stat, dyn, wsf, flag);
    }
    hipLaunchKernelGGL(k3_seq, dim3(128), dim3(1024), 0, stream,
                       stat, decin, Whh, bhh, aW, av, pv, wsf, allow_general, out);
}

// Round 15
// 1659.546 us; speedup vs baseline: 2.5231x; 1.0659x over previous
//
#include <hip/hip_runtime.h>
#include <hip/hip_bf16.h>
#include <math.h>

// Problem dims
#define BB   128   // batch
#define SS   128   // sequence / positions
#define HH   256   // hidden
#define DYNN 192   // dynamic channels
#define LC   128   // W_hh rows cached in LDS (rows 0..LC-1)

// ws layout (float offsets)
#define OFF_FLAG  0
#define OFF_G     64
#define OFF_G0    (OFF_G + 1536)
#define OFF_M1A   (OFF_G0 + 768)
#define OFF_CA    (OFF_M1A + 512)
#define OFF_M1P   (OFF_CA + 256)
#define OFF_CP    (OFF_M1P + 512)
#define OFF_M3P   (OFF_CP + 256)
#define OFF_CP3   (OFF_M3P + 512)
#define OFF_LM    (OFF_CP3 + 256)
#define OFF_M2A   (OFF_LM + 16384)
#define OFF_M2P   (OFF_M2A + 49152)
#define OFF_BASEA (OFF_M2P + 49152)
#define OFF_BASEP (OFF_BASEA + 4194304)
#define OFF_END   (OFF_BASEP + 4194304)

__device__ __forceinline__ float tanh_fast(float x) {
    float e = __builtin_amdgcn_exp2f(x * 2.885390081777927f); // 2*log2(e)
    return 1.0f - 2.0f * __builtin_amdgcn_rcpf(e + 1.0f);
}

// Y-group spin barrier: monotone LDS counter, wave leaders add 1. (proven R3/R5/R6)
__device__ __forceinline__ void ybar(int* cnt, bool arrive, int target) {
    if (arrive && (threadIdx.x & 63) == 0)
        __hip_atomic_fetch_add(cnt, 1, __ATOMIC_RELEASE, __HIP_MEMORY_SCOPE_WORKGROUP);
    while (__hip_atomic_load(cnt, __ATOMIC_ACQUIRE, __HIP_MEMORY_SCOPE_WORKGROUP) < target)
        __builtin_amdgcn_s_sleep(1);
}

// K1: logmask + "dynamic is nonzero" flag
__global__ void k1_logmask(const float* __restrict__ dyn, float* __restrict__ lm,
                           int* __restrict__ flag) {
    int g = blockIdx.x * 256 + threadIdx.x;
    if (g >= BB * SS) return;
    int b = g >> 7, s = g & 127;
    const float* p = dyn + (size_t)b * DYNN * SS + s;
    float mv = 0.f, m1 = 0.f, m2 = 0.f;
    bool nz = false;
    for (int i = 0; i < 64; ++i)        { float v = p[(size_t)i * SS]; mv += v; nz |= (v != 0.f); }
    for (int i = 64; i < 128; ++i)      { float v = p[(size_t)i * SS]; m1 += v; nz |= (v != 0.f); }
    for (int i = 128; i < 192; ++i)     { float v = p[(size_t)i * SS]; m2 += v; nz |= (v != 0.f); }
    float dm = m1 * m2 + mv;
    lm[g] = (dm != 0.f) ? -__builtin_inff() : 0.f;
    if (nz) atomicOr(flag, 1);
}

// K0a: small weight folds (rank-2 eliminations)
__global__ void k0a_folds(const float* __restrict__ Wih, const float* __restrict__ bih,
                          const float* __restrict__ dW,  const float* __restrict__ db,
                          const float* __restrict__ aW,  const float* __restrict__ pW,
                          const float* __restrict__ esW, const float* __restrict__ esb,
                          const float* __restrict__ edb, float* __restrict__ wsf) {
    int idx = blockIdx.x * 256 + threadIdx.x;
    float* G   = wsf + OFF_G;
    float* g0  = wsf + OFF_G0;
    float* M1a = wsf + OFF_M1A;
    float* ca  = wsf + OFF_CA;
    float* M1p = wsf + OFF_M1P;
    float* cp  = wsf + OFF_CP;
    float* M3p = wsf + OFF_M3P;
    float* cp3 = wsf + OFF_CP3;
    if (idx < 1536) {
        int r = idx >> 1, j = idx & 1;
        float a = 0.f;
        for (int k = 0; k < 256; ++k) a += Wih[r * 256 + k] * dW[k * 2 + j];
        G[idx] = a;
    } else if (idx < 2304) {
        int r = idx - 1536;
        float a = 0.f;
        for (int k = 0; k < 256; ++k) a += Wih[r * 256 + k] * db[k];
        g0[r] = a + bih[r];
    } else if (idx < 2816) {
        int t = idx - 2304; int h = t >> 1, j = t & 1;
        float a = 0.f;
        for (int k = 0; k < 256; ++k) a += aW[h * 768 + k] * esW[k * 2 + j];
        M1a[t] = a;
    } else if (idx < 3072) {
        int h = idx - 2816;
        float a = 0.f, b2 = 0.f;
        for (int k = 0; k < 256; ++k) a  += aW[h * 768 + k]       * esb[k];
        for (int k = 0; k < 256; ++k) b2 += aW[h * 768 + 256 + k] * edb[k];
        ca[h] = a + b2;
    } else if (idx < 3584) {
        int t = idx - 3072; int h = t >> 1, j = t & 1;
        float a = 0.f;
        for (int k = 0; k < 256; ++k) a += pW[h * 768 + k] * esW[k * 2 + j];
        M1p[t] = a;
    } else if (idx < 3840) {
        int h = idx - 3584;
        float a = 0.f, b2 = 0.f;
        for (int k = 0; k < 256; ++k) a  += pW[h * 768 + k]       * esb[k];
        for (int k = 0; k < 256; ++k) b2 += pW[h * 768 + 256 + k] * edb[k];
        cp[h] = a + b2;
    } else if (idx < 4352) {
        int t = idx - 3840; int h = t >> 1, j = t & 1;
        float a = 0.f;
        for (int k = 0; k < 256; ++k) a += pW[h * 768 + 512 + k] * esW[k * 2 + j];
        M3p[t] = a;
    } else if (idx < 4608) {
        int h = idx - 4352;
        float a = 0.f;
        for (int k = 0; k < 256; ++k) a += pW[h * 768 + 512 + k] * esb[k];
        cp3[h] = a;
    }
}

// K0b: M2a/M2p folds for the general (dynamic != 0) path
__global__ void k0b_m2(const float* __restrict__ aW, const float* __restrict__ pW,
                       const float* __restrict__ edW, float* __restrict__ wsf,
                       const int* __restrict__ flag) {
    if (*flag == 0) return;
    int idx = blockIdx.x * 256 + threadIdx.x;
    if (idx >= 2 * 49152) return;
    int which = idx / 49152;
    int t = idx % 49152;
    int h = t / DYNN, i = t % DYNN;
    const float* W = which ? pW : aW;
    float a = 0.f;
    for (int k = 0; k < 256; ++k) a += W[h * 768 + 256 + k] * edW[k * DYNN + i];
    wsf[(which ? OFF_M2P : OFF_M2A) + t] = a;
}

// K2: general-path bases, layout [b][s][h]
__global__ void k2_bases(const float* __restrict__ stat, const float* __restrict__ dyn,
                         float* __restrict__ wsf, const int* __restrict__ flag) {
    if (*flag == 0) return;
    __shared__ float col[DYNN];
    __shared__ float s01[2];
    const float* M1a = wsf + OFF_M1A; const float* ca  = wsf + OFF_CA;
    const float* M1p = wsf + OFF_M1P; const float* cp  = wsf + OFF_CP;
    const float* M2a = wsf + OFF_M2A; const float* M2p = wsf + OFF_M2P;
    float* basea = wsf + OFF_BASEA;   float* basep = wsf + OFF_BASEP;
    for (int pair = blockIdx.x; pair < BB * SS; pair += gridDim.x) {
        int b = pair >> 7, s = pair & 127;
        if (threadIdx.x < DYNN) col[threadIdx.x] = dyn[((size_t)b * DYNN + threadIdx.x) * SS + s];
        if (threadIdx.x == DYNN) {
            s01[0] = stat[((size_t)b * 3 + 1) * SS + s];
            s01[1] = stat[((size_t)b * 3 + 2) * SS + s];
        }
        __syncthreads();
        int h = threadIdx.x;
        float aa = fmaf(M1a[h * 2], s01[0], fmaf(M1a[h * 2 + 1], s01[1], ca[h]));
        float pp = fmaf(M1p[h * 2], s01[0], fmaf(M1p[h * 2 + 1], s01[1], cp[h]));
        for (int i = 0; i < DYNN; ++i) {
            aa = fmaf(M2a[h * DYNN + i], col[i], aa);
            pp = fmaf(M2p[h * DYNN + i], col[i], pp);
        }
        basea[((size_t)b * SS + s) * HH + h] = aa;
        basep[((size_t)b * SS + s) * HH + h] = pp;
        __syncthreads();
    }
}

// Row dot-product: fmaf nest + width-16 reduce, bitwise identical across rounds.
#define DOT16(W0, W1, W2, W3)                                                                    \
    float acc = 0.f;                                                                             \
    acc = fmaf(W0.x, hx0.x, fmaf(W0.y, hx0.y, fmaf(W0.z, hx0.z, fmaf(W0.w, hx0.w, acc))));       \
    acc = fmaf(W1.x, hx1.x, fmaf(W1.y, hx1.y, fmaf(W1.z, hx1.z, fmaf(W1.w, hx1.w, acc))));       \
    acc = fmaf(W2.x, hx2.x, fmaf(W2.y, hx2.y, fmaf(W2.z, hx2.z, fmaf(W2.w, hx2.w, acc))));       \
    acc = fmaf(W3.x, hx3.x, fmaf(W3.y, hx3.y, fmaf(W3.z, hx3.z, fmaf(W3.w, hx3.w, acc))));       \
    acc += __shfl_xor(acc, 1, 16); acc += __shfl_xor(acc, 2, 16);                                \
    acc += __shfl_xor(acc, 4, 16); acc += __shfl_xor(acc, 8, 16);

// K3: sequential decoder, one WG per batch (grid=128, 1024 threads).
//   waves 0-7  (X): gh(t+1) = W_hh*h; rows 0..127 from LDS cache, rest from L2.
//   waves 8-15 (Y): t1=A3*h -> attn -> softmax -> ptr -> argmax (ybar-chained).
// R15 = R11 (best, 1621us) + PER-BLOCK ROW-ORDER ROTATION in the two streamed
// loops. All 128 blocks read the SAME weights each step in the same order;
// the 16 CUs/XCD then hit the same L2 lines simultaneously and the owning
// slice serializes responses (suspected cause of the ~71 GB/s/CU plateau).
// Rotating each block's loop start decorrelates slice traffic. Per-row
// arithmetic is order-independent and bitwise identical.
__global__ __launch_bounds__(1024) void k3_seq(
    const float* __restrict__ stat, const float* __restrict__ dec_inp,
    const float* __restrict__ Whh, const float* __restrict__ bhh_g,
    const float* __restrict__ aW, const float* __restrict__ av,
    const float* __restrict__ pv, const float* __restrict__ wsf,
    int allow_general, float* __restrict__ out) {
    const int b = blockIdx.x;
    const int tid = threadIdx.x;

    __shared__ float sh_whh[LC][256];           // 128 KB weight cache
    __shared__ float sh_gh[768], sh_hv[256], sh_t1[256], sh_a[128];
    __shared__ float sh_sp0[128], sh_sp1[128], sh_lm[128];
    __shared__ float4 qa1[64], qa2[64], qva[64];   // attn logits quad operands
    __shared__ float4 qp1[64], qp2[64], qvp[64];   // ptr  logits quad operands
    __shared__ float sh_M3p[512];
    __shared__ float sh_ca[256], sh_cp[256], sh_cp3[256];
    __shared__ float sh_G[1536], sh_g0[768], sh_bhh[768];
    __shared__ float sh_scal[4];
    __shared__ int ycnt;

    const float* G_   = wsf + OFF_G;   const float* g0_  = wsf + OFF_G0;
    const float* M1a_ = wsf + OFF_M1A; const float* ca_  = wsf + OFF_CA;
    const float* M1p_ = wsf + OFF_M1P; const float* cp_  = wsf + OFF_CP;
    const float* M3p_ = wsf + OFF_M3P; const float* cp3_ = wsf + OFF_CP3;
    const float* lm_  = wsf + OFF_LM;
    const float* basea = wsf + OFF_BASEA;
    const float* basep = wsf + OFF_BASEP;
    const int* flag = (const int*)wsf;

    // W_hh rows 0..LC-1 into LDS (float4 cooperative copy, once)
    {
        float4* dst = (float4*)&sh_whh[0][0];
        const float4* src = (const float4*)Whh;
        for (int i = tid; i < LC * 64; i += 1024) dst[i] = src[i];
    }
    for (int i = tid; i < 1536; i += 1024) sh_G[i] = G_[i];
    for (int i = tid; i < 768; i += 1024) {
        sh_g0[i] = g0_[i];
        float bv = bhh_g[i];
        sh_bhh[i] = bv;
        sh_gh[i] = bv;            // gh for step 0: h0 = 0 => gh = b_hh
    }
    for (int i = tid; i < 512; i += 1024) sh_M3p[i] = M3p_[i];
    for (int i = tid; i < 256; i += 1024) {
        sh_ca[i] = ca_[i]; sh_cp[i] = cp_[i]; sh_cp3[i] = cp3_[i];
        sh_hv[i] = 0.f;
    }
    for (int i = tid; i < 128; i += 1024) {
        sh_sp0[i] = stat[((size_t)b * 3 + 1) * SS + i];
        sh_sp1[i] = stat[((size_t)b * 3 + 2) * SS + i];
        sh_lm[i]  = lm_[b * SS + i];
    }
    // quad-pack logit operands (step-invariant): 4 i per float4
    if (tid < 64) {
        int q = tid;
        qa1[q] = make_float4(M1a_[(4*q+0)*2], M1a_[(4*q+1)*2], M1a_[(4*q+2)*2], M1a_[(4*q+3)*2]);
        qa2[q] = make_float4(M1a_[(4*q+0)*2+1], M1a_[(4*q+1)*2+1], M1a_[(4*q+2)*2+1], M1a_[(4*q+3)*2+1]);
        qva[q] = make_float4(av[4*q+0], av[4*q+1], av[4*q+2], av[4*q+3]);
    } else if (tid < 128) {
        int q = tid - 64;
        qp1[q] = make_float4(M1p_[(4*q+0)*2], M1p_[(4*q+1)*2], M1p_[(4*q+2)*2], M1p_[(4*q+3)*2]);
        qp2[q] = make_float4(M1p_[(4*q+0)*2+1], M1p_[(4*q+1)*2+1], M1p_[(4*q+2)*2+1], M1p_[(4*q+3)*2+1]);
        qvp[q] = make_float4(pv[4*q+0], pv[4*q+1], pv[4*q+2], pv[4*q+3]);
    }
    if (tid == 0) {
        sh_scal[0] = dec_inp[b * 2 + 0];
        sh_scal[1] = dec_inp[b * 2 + 1];
        ycnt = 0;
    }
    const bool dz = (!allow_general) || (*flag == 0);
    const int rot20 = b % 20;     // X streamed-loop rotation
    const int rot8  = b & 7;      // Y1 streamed-loop rotation
    __syncthreads();

    for (int t = 0; t < SS; ++t) {
        // ---- GRU gates (threads 0..255): h(t) from sh_gh + rank-2 gi fold
        if (tid < 256) {
            int k = tid;
            float d0 = sh_scal[0], d1 = sh_scal[1];
            float gr = fmaf(sh_G[k * 2],          d0, fmaf(sh_G[k * 2 + 1],          d1, sh_g0[k]));
            float gz = fmaf(sh_G[(k + 256) * 2],  d0, fmaf(sh_G[(k + 256) * 2 + 1],  d1, sh_g0[k + 256]));
            float gn = fmaf(sh_G[(k + 512) * 2],  d0, fmaf(sh_G[(k + 512) * 2 + 1],  d1, sh_g0[k + 512]));
            float r = 1.f / (1.f + expf(-(gr + sh_gh[k])));
            float z = 1.f / (1.f + expf(-(gz + sh_gh[k + 256])));
            float n = tanhf(gn + r * sh_gh[k + 512]);
            sh_hv[k] = (1.f - z) * n + z * sh_hv[k];
        }
        __syncthreads();      // h(t) visible to X and Y

        if (tid < 512) {
            // ===== X: sh_gh <- W_hh * h(t) + b_hh (for step t+1) =====
            if (t + 1 < SS) {
                const int xg = tid >> 4, xj = tid & 15;   // 32 row-groups x 16 lanes
                float4 hx0 = ((const float4*)sh_hv)[xj];
                float4 hx1 = ((const float4*)sh_hv)[xj + 16];
                float4 hx2 = ((const float4*)sh_hv)[xj + 32];
                float4 hx3 = ((const float4*)sh_hv)[xj + 48];
                // rows 0..127 from LDS cache
                #pragma unroll
                for (int k = 0; k < 4; ++k) {
                    int r = xg + 32 * k;
                    const float4* Wr = (const float4*)&sh_whh[r][0];
                    float4 w0 = Wr[xj], w1 = Wr[xj + 16], w2 = Wr[xj + 32], w3 = Wr[xj + 48];
                    DOT16(w0, w1, w2, w3)
                    if (xj == 0) sh_gh[r] = acc + sh_bhh[r];
                }
                // rows 128..767 streamed from L2, block-rotated order
                #pragma unroll 2
                for (int k0 = 4; k0 < 24; ++k0) {
                    int k = k0 + rot20; if (k >= 24) k -= 20;
                    int r = xg + 32 * k;
                    const float4* Wr = (const float4*)(Whh + (size_t)r * 256);
                    float4 w0 = Wr[xj], w1 = Wr[xj + 16], w2 = Wr[xj + 32], w3 = Wr[xj + 48];
                    DOT16(w0, w1, w2, w3)
                    if (xj == 0) sh_gh[r] = acc + sh_bhh[r];
                }
            }
        } else {
            // ===== Y: t1 -> attn -> softmax -> ptr -> argmax =====
            const int yt = tid - 512;
            const int ybase = t * 25;

            // Y1: t1 = A3 * h (stream A3 from L2, block-rotated) (+ ca on zero path)
            {
                const int yq = yt >> 4, yj = yt & 15;   // 32 row-groups
                float4 hx0 = ((const float4*)sh_hv)[yj];
                float4 hx1 = ((const float4*)sh_hv)[yj + 16];
                float4 hx2 = ((const float4*)sh_hv)[yj + 32];
                float4 hx3 = ((const float4*)sh_hv)[yj + 48];
                #pragma unroll 2
                for (int k0 = 0; k0 < 8; ++k0) {
                    int k = (k0 + rot8) & 7;
                    int r = yq + 32 * k;
                    const float4* Wr = (const float4*)(aW + (size_t)r * 768 + 512);
                    float4 w0 = Wr[yj], w1 = Wr[yj + 16], w2 = Wr[yj + 32], w3 = Wr[yj + 48];
                    DOT16(w0, w1, w2, w3)
                    if (yj == 0) sh_t1[r] = acc + (dz ? sh_ca[r] : 0.f);
                }
            }
            ybar(&ycnt, true, ybase + 8);

            // Y2: attn logits (4 threads per s, quad-vectorized)
            {
                int s = yt >> 2, g = yt & 3;
                float acc = 0.f;
                if (dz) {
                    float s0 = sh_sp0[s], s1 = sh_sp1[s];
                    #pragma unroll 4
                    for (int q = g; q < 64; q += 4) {
                        float4 A1 = qa1[q], A2 = qa2[q], V = qva[q];
                        float4 T = ((const float4*)sh_t1)[q];
                        acc = fmaf(V.x, tanh_fast(fmaf(A1.x, s0, fmaf(A2.x, s1, T.x))), acc);
                        acc = fmaf(V.y, tanh_fast(fmaf(A1.y, s0, fmaf(A2.y, s1, T.y))), acc);
                        acc = fmaf(V.z, tanh_fast(fmaf(A1.z, s0, fmaf(A2.z, s1, T.z))), acc);
                        acc = fmaf(V.w, tanh_fast(fmaf(A1.w, s0, fmaf(A2.w, s1, T.w))), acc);
                    }
                } else {
                    const float* bb = basea + ((size_t)b * SS + s) * HH;
                    #pragma unroll 4
                    for (int q = g; q < 64; q += 4) {
                        float4 V = qva[q];
                        float4 T = ((const float4*)sh_t1)[q];
                        float4 B = *(const float4*)(bb + q * 4);
                        acc = fmaf(V.x, tanh_fast(B.x + T.x), acc);
                        acc = fmaf(V.y, tanh_fast(B.y + T.y), acc);
                        acc = fmaf(V.z, tanh_fast(B.z + T.z), acc);
                        acc = fmaf(V.w, tanh_fast(B.w + T.w), acc);
                    }
                }
                acc += __shfl_xor(acc, 1, 4); acc += __shfl_xor(acc, 2, 4);
                if (g == 0) sh_a[s] = acc;
            }
            ybar(&ycnt, true, ybase + 16);

            // Y3: softmax + context + t2 fold (wave 8 only)
            if (yt < 64) {
                int ln = yt;
                float v0 = sh_a[ln], v1 = sh_a[ln + 64];
                float m = fmaxf(v0, v1);
                for (int msk = 1; msk < 64; msk <<= 1) m = fmaxf(m, __shfl_xor(m, msk, 64));
                float e0 = expf(v0 - m), e1 = expf(v1 - m);
                float S = e0 + e1;
                float c0 = e0 * sh_sp0[ln] + e1 * sh_sp0[ln + 64];
                float c1 = e0 * sh_sp1[ln] + e1 * sh_sp1[ln + 64];
                for (int msk = 1; msk < 64; msk <<= 1) {
                    S  += __shfl_xor(S,  msk, 64);
                    c0 += __shfl_xor(c0, msk, 64);
                    c1 += __shfl_xor(c1, msk, 64);
                }
                float C0 = c0 / S, C1 = c1 / S;
                #pragma unroll
                for (int q = 0; q < 4; ++q) {
                    int k2 = ln + 64 * q;
                    float v = fmaf(sh_M3p[k2 * 2], C0, fmaf(sh_M3p[k2 * 2 + 1], C1, sh_cp3[k2]));
                    sh_t1[k2] = v + (dz ? sh_cp[k2] : 0.f);
                }
                ybar(&ycnt, true, ybase + 17);
            } else {
                ybar(&ycnt, false, ybase + 17);
            }

            // Y4: ptr logits (quad-vectorized)
            {
                int s = yt >> 2, g = yt & 3;
                float acc = 0.f;
                if (dz) {
                    float s0 = sh_sp0[s], s1 = sh_sp1[s];
                    #pragma unroll 4
                    for (int q = g; q < 64; q += 4) {
                        float4 A1 = qp1[q], A2 = qp2[q], V = qvp[q];
                        float4 T = ((const float4*)sh_t1)[q];
                        acc = fmaf(V.x, tanh_fast(fmaf(A1.x, s0, fmaf(A2.x, s1, T.x))), acc);
                        acc = fmaf(V.y, tanh_fast(fmaf(A1.y, s0, fmaf(A2.y, s1, T.y))), acc);
                        acc = fmaf(V.z, tanh_fast(fmaf(A1.z, s0, fmaf(A2.z, s1, T.z))), acc);
                        acc = fmaf(V.w, tanh_fast(fmaf(A1.w, s0, fmaf(A2.w, s1, T.w))), acc);
                    }
                } else {
                    const float* bb = basep + ((size_t)b * SS + s) * HH;
                    #pragma unroll 4
                    for (int q = g; q < 64; q += 4) {
                        float4 V = qvp[q];
                        float4 T = ((const float4*)sh_t1)[q];
                        float4 B = *(const float4*)(bb + q * 4);
                        acc = fmaf(V.x, tanh_fast(B.x + T.x), acc);
                        acc = fmaf(V.y, tanh_fast(B.y + T.y), acc);
                        acc = fmaf(V.z, tanh_fast(B.z + T.z), acc);
                        acc = fmaf(V.w, tanh_fast(B.w + T.w), acc);
                    }
                }
                acc += __shfl_xor(acc, 1, 4); acc += __shfl_xor(acc, 2, 4);
                if (g == 0) sh_a[s] = acc;
            }
            ybar(&ycnt, true, ybase + 25);

            // Y5: masked argmax + logp + dec_in update (wave 8 only)
            if (yt < 64) {
                int ln = yt;
                float l0 = sh_a[ln] + sh_lm[ln];
                float l1 = sh_a[ln + 64] + sh_lm[ln + 64];
                float v; int idx;
                if (l0 >= l1) { v = l0; idx = ln; } else { v = l1; idx = ln + 64; }
                for (int msk = 1; msk < 64; msk <<= 1) {
                    float ov = __shfl_xor(v, msk, 64);
                    int   oi = __shfl_xor(idx, msk, 64);
                    if (ov > v || (ov == v && oi < idx)) { v = ov; idx = oi; }
                }
                float S = expf(l0 - v) + expf(l1 - v);
                for (int msk = 1; msk < 64; msk <<= 1) S += __shfl_xor(S, msk, 64);
                if (ln == 0) {
                    out[b * SS + t] = (float)idx;
                    out[BB * SS + b * SS + t] = -logf(S);
                    sh_scal[0] = sh_sp0[idx];
                    sh_scal[1] = sh_sp1[idx];
                }
            }
        }
        __syncthreads();      // gh(t+1), dec_in, Y buffers all settled
    }
}

extern "C" void kernel_launch(void* const* d_in, const int* in_sizes, int n_in,
                              void* d_out, int out_size, void* d_ws, size_t ws_size,
                              hipStream_t stream) {
    const float* stat  = (const float*)d_in[0];
    const float* dyn   = (const float*)d_in[1];
    const float* decin = (const float*)d_in[2];
    const float* esW   = (const float*)d_in[3];
    const float* esb   = (const float*)d_in[4];
    const float* edW   = (const float*)d_in[5];
    const float* edb   = (const float*)d_in[6];
    const float* dW    = (const float*)d_in[7];
    const float* db    = (const float*)d_in[8];
    const float* Wih   = (const float*)d_in[9];
    const float* Whh   = (const float*)d_in[10];
    const float* bih   = (const float*)d_in[11];
    const float* bhh   = (const float*)d_in[12];
    const float* av    = (const float*)d_in[13];
    const float* aW    = (const float*)d_in[14];
    const float* pv    = (const float*)d_in[15];
    const float* pW    = (const float*)d_in[16];
    float* wsf = (float*)d_ws;
    int* flag  = (int*)d_ws;
    float* out = (float*)d_out;

    int allow_general = (ws_size >= (size_t)OFF_END * 4) ? 1 : 0;

    hipMemsetAsync(d_ws, 0, 256, stream);
    hipLaunchKernelGGL(k1_logmask, dim3(64), dim3(256), 0, stream, dyn, wsf + OFF_LM, flag);
    hipLaunchKernelGGL(k0a_folds, dim3(18), dim3(256), 0, stream,
                       Wih, bih, dW, db, aW, pW, esW, esb, edb, wsf);
    if (allow_general) {
        hipLaunchKernelGGL(k0b_m2, dim3(384), dim3(256), 0, stream, aW, pW, edW, wsf, flag);
        hipLaunchKernelGGL(k2_bases, dim3(256), dim3(256), 0, stream, stat, dyn, wsf, flag);
    }
    hipLaunchKernelGGL(k3_seq, dim3(128), dim3(1024), 0, stream,
                       stat, decin, Whh, bhh, aW, av, pv, wsf, allow_general, out);
}

// Round 16
// 1619.262 us; speedup vs baseline: 2.5858x; 1.0249x over previous
//
#include <hip/hip_runtime.h>
#include <hip/hip_bf16.h>
#include <math.h>

// Problem dims
#define BB   128   // batch
#define SS   128   // sequence / positions
#define HH   256   // hidden
#define DYNN 192   // dynamic channels
#define LC   128   // W_hh rows cached in LDS (rows 0..LC-1)

// ws layout (float offsets)
#define OFF_FLAG  0
#define OFF_G     64
#define OFF_G0    (OFF_G + 1536)
#define OFF_M1A   (OFF_G0 + 768)
#define OFF_CA    (OFF_M1A + 512)
#define OFF_M1P   (OFF_CA + 256)
#define OFF_CP    (OFF_M1P + 512)
#define OFF_M3P   (OFF_CP + 256)
#define OFF_CP3   (OFF_M3P + 512)
#define OFF_LM    (OFF_CP3 + 256)
#define OFF_M2A   (OFF_LM + 16384)
#define OFF_M2P   (OFF_M2A + 49152)
#define OFF_BASEA (OFF_M2P + 49152)
#define OFF_BASEP (OFF_BASEA + 4194304)
#define OFF_END   (OFF_BASEP + 4194304)

__device__ __forceinline__ float tanh_fast(float x) {
    float e = __builtin_amdgcn_exp2f(x * 2.885390081777927f); // 2*log2(e)
    return 1.0f - 2.0f * __builtin_amdgcn_rcpf(e + 1.0f);
}

// Y-group spin barrier: monotone LDS counter, wave leaders add 1. (proven R3/R5/R6)
__device__ __forceinline__ void ybar(int* cnt, bool arrive, int target) {
    if (arrive && (threadIdx.x & 63) == 0)
        __hip_atomic_fetch_add(cnt, 1, __ATOMIC_RELEASE, __HIP_MEMORY_SCOPE_WORKGROUP);
    while (__hip_atomic_load(cnt, __ATOMIC_ACQUIRE, __HIP_MEMORY_SCOPE_WORKGROUP) < target)
        __builtin_amdgcn_s_sleep(1);
}

// K1: logmask + "dynamic is nonzero" flag
__global__ void k1_logmask(const float* __restrict__ dyn, float* __restrict__ lm,
                           int* __restrict__ flag) {
    int g = blockIdx.x * 256 + threadIdx.x;
    if (g >= BB * SS) return;
    int b = g >> 7, s = g & 127;
    const float* p = dyn + (size_t)b * DYNN * SS + s;
    float mv = 0.f, m1 = 0.f, m2 = 0.f;
    bool nz = false;
    for (int i = 0; i < 64; ++i)        { float v = p[(size_t)i * SS]; mv += v; nz |= (v != 0.f); }
    for (int i = 64; i < 128; ++i)      { float v = p[(size_t)i * SS]; m1 += v; nz |= (v != 0.f); }
    for (int i = 128; i < 192; ++i)     { float v = p[(size_t)i * SS]; m2 += v; nz |= (v != 0.f); }
    float dm = m1 * m2 + mv;
    lm[g] = (dm != 0.f) ? -__builtin_inff() : 0.f;
    if (nz) atomicOr(flag, 1);
}

// K0a: small weight folds (rank-2 eliminations)
__global__ void k0a_folds(const float* __restrict__ Wih, const float* __restrict__ bih,
                          const float* __restrict__ dW,  const float* __restrict__ db,
                          const float* __restrict__ aW,  const float* __restrict__ pW,
                          const float* __restrict__ esW, const float* __restrict__ esb,
                          const float* __restrict__ edb, float* __restrict__ wsf) {
    int idx = blockIdx.x * 256 + threadIdx.x;
    float* G   = wsf + OFF_G;
    float* g0  = wsf + OFF_G0;
    float* M1a = wsf + OFF_M1A;
    float* ca  = wsf + OFF_CA;
    float* M1p = wsf + OFF_M1P;
    float* cp  = wsf + OFF_CP;
    float* M3p = wsf + OFF_M3P;
    float* cp3 = wsf + OFF_CP3;
    if (idx < 1536) {
        int r = idx >> 1, j = idx & 1;
        float a = 0.f;
        for (int k = 0; k < 256; ++k) a += Wih[r * 256 + k] * dW[k * 2 + j];
        G[idx] = a;
    } else if (idx < 2304) {
        int r = idx - 1536;
        float a = 0.f;
        for (int k = 0; k < 256; ++k) a += Wih[r * 256 + k] * db[k];
        g0[r] = a + bih[r];
    } else if (idx < 2816) {
        int t = idx - 2304; int h = t >> 1, j = t & 1;
        float a = 0.f;
        for (int k = 0; k < 256; ++k) a += aW[h * 768 + k] * esW[k * 2 + j];
        M1a[t] = a;
    } else if (idx < 3072) {
        int h = idx - 2816;
        float a = 0.f, b2 = 0.f;
        for (int k = 0; k < 256; ++k) a  += aW[h * 768 + k]       * esb[k];
        for (int k = 0; k < 256; ++k) b2 += aW[h * 768 + 256 + k] * edb[k];
        ca[h] = a + b2;
    } else if (idx < 3584) {
        int t = idx - 3072; int h = t >> 1, j = t & 1;
        float a = 0.f;
        for (int k = 0; k < 256; ++k) a += pW[h * 768 + k] * esW[k * 2 + j];
        M1p[t] = a;
    } else if (idx < 3840) {
        int h = idx - 3584;
        float a = 0.f, b2 = 0.f;
        for (int k = 0; k < 256; ++k) a  += pW[h * 768 + k]       * esb[k];
        for (int k = 0; k < 256; ++k) b2 += pW[h * 768 + 256 + k] * edb[k];
        cp[h] = a + b2;
    } else if (idx < 4352) {
        int t = idx - 3840; int h = t >> 1, j = t & 1;
        float a = 0.f;
        for (int k = 0; k < 256; ++k) a += pW[h * 768 + 512 + k] * esW[k * 2 + j];
        M3p[t] = a;
    } else if (idx < 4608) {
        int h = idx - 4352;
        float a = 0.f;
        for (int k = 0; k < 256; ++k) a += pW[h * 768 + 512 + k] * esb[k];
        cp3[h] = a;
    }
}

// K0b: M2a/M2p folds for the general (dynamic != 0) path
__global__ void k0b_m2(const float* __restrict__ aW, const float* __restrict__ pW,
                       const float* __restrict__ edW, float* __restrict__ wsf,
                       const int* __restrict__ flag) {
    if (*flag == 0) return;
    int idx = blockIdx.x * 256 + threadIdx.x;
    if (idx >= 2 * 49152) return;
    int which = idx / 49152;
    int t = idx % 49152;
    int h = t / DYNN, i = t % DYNN;
    const float* W = which ? pW : aW;
    float a = 0.f;
    for (int k = 0; k < 256; ++k) a += W[h * 768 + 256 + k] * edW[k * DYNN + i];
    wsf[(which ? OFF_M2P : OFF_M2A) + t] = a;
}

// K2: general-path bases, layout [b][s][h]
__global__ void k2_bases(const float* __restrict__ stat, const float* __restrict__ dyn,
                         float* __restrict__ wsf, const int* __restrict__ flag) {
    if (*flag == 0) return;
    __shared__ float col[DYNN];
    __shared__ float s01[2];
    const float* M1a = wsf + OFF_M1A; const float* ca  = wsf + OFF_CA;
    const float* M1p = wsf + OFF_M1P; const float* cp  = wsf + OFF_CP;
    const float* M2a = wsf + OFF_M2A; const float* M2p = wsf + OFF_M2P;
    float* basea = wsf + OFF_BASEA;   float* basep = wsf + OFF_BASEP;
    for (int pair = blockIdx.x; pair < BB * SS; pair += gridDim.x) {
        int b = pair >> 7, s = pair & 127;
        if (threadIdx.x < DYNN) col[threadIdx.x] = dyn[((size_t)b * DYNN + threadIdx.x) * SS + s];
        if (threadIdx.x == DYNN) {
            s01[0] = stat[((size_t)b * 3 + 1) * SS + s];
            s01[1] = stat[((size_t)b * 3 + 2) * SS + s];
        }
        __syncthreads();
        int h = threadIdx.x;
        float aa = fmaf(M1a[h * 2], s01[0], fmaf(M1a[h * 2 + 1], s01[1], ca[h]));
        float pp = fmaf(M1p[h * 2], s01[0], fmaf(M1p[h * 2 + 1], s01[1], cp[h]));
        for (int i = 0; i < DYNN; ++i) {
            aa = fmaf(M2a[h * DYNN + i], col[i], aa);
            pp = fmaf(M2p[h * DYNN + i], col[i], pp);
        }
        basea[((size_t)b * SS + s) * HH + h] = aa;
        basep[((size_t)b * SS + s) * HH + h] = pp;
        __syncthreads();
    }
}

// K3: sequential decoder, one WG per batch (grid=128, 1024 threads).
//   waves 0-7  (X): gh(t+1) = W_hh*h; rows 0..127 from LDS cache, rest from L2.
//   waves 8-15 (Y): t1=A3*h -> attn -> softmax -> ptr -> argmax (ybar-chained).
// FINAL (= R11, best measured 1621 us): stream floor = 902 KB/step at the
// measured ~71 GB/s/CU same-data L2 ingest rate -> 12.65 us/step; measured
// 12.67 us/step (99.8% of model). All other levers measured and closed:
// depth (compiler 64-VGPR cap, 5 attempts), DMA (-29%), cross-WG sync (-5x),
// work-shift (-9%), slice decorrelation (neutral).
__global__ __launch_bounds__(1024) void k3_seq(
    const float* __restrict__ stat, const float* __restrict__ dec_inp,
    const float* __restrict__ Whh, const float* __restrict__ bhh_g,
    const float* __restrict__ aW, const float* __restrict__ av,
    const float* __restrict__ pv, const float* __restrict__ wsf,
    int allow_general, float* __restrict__ out) {
    const int b = blockIdx.x;
    const int tid = threadIdx.x;

    __shared__ float sh_whh[LC][256];           // 128 KB weight cache
    __shared__ float sh_gh[768], sh_hv[256], sh_t1[256], sh_a[128];
    __shared__ float sh_sp0[128], sh_sp1[128], sh_lm[128];
    __shared__ float4 qa1[64], qa2[64], qva[64];   // attn logits quad operands
    __shared__ float4 qp1[64], qp2[64], qvp[64];   // ptr  logits quad operands
    __shared__ float sh_M3p[512];
    __shared__ float sh_ca[256], sh_cp[256], sh_cp3[256];
    __shared__ float sh_G[1536], sh_g0[768], sh_bhh[768];
    __shared__ float sh_scal[4];
    __shared__ int ycnt;

    const float* G_   = wsf + OFF_G;   const float* g0_  = wsf + OFF_G0;
    const float* M1a_ = wsf + OFF_M1A; const float* ca_  = wsf + OFF_CA;
    const float* M1p_ = wsf + OFF_M1P; const float* cp_  = wsf + OFF_CP;
    const float* M3p_ = wsf + OFF_M3P; const float* cp3_ = wsf + OFF_CP3;
    const float* lm_  = wsf + OFF_LM;
    const float* basea = wsf + OFF_BASEA;
    const float* basep = wsf + OFF_BASEP;
    const int* flag = (const int*)wsf;

    // W_hh rows 0..LC-1 into LDS (float4 cooperative copy, once)
    {
        float4* dst = (float4*)&sh_whh[0][0];
        const float4* src = (const float4*)Whh;
        for (int i = tid; i < LC * 64; i += 1024) dst[i] = src[i];
    }
    for (int i = tid; i < 1536; i += 1024) sh_G[i] = G_[i];
    for (int i = tid; i < 768; i += 1024) {
        sh_g0[i] = g0_[i];
        float bv = bhh_g[i];
        sh_bhh[i] = bv;
        sh_gh[i] = bv;            // gh for step 0: h0 = 0 => gh = b_hh
    }
    for (int i = tid; i < 512; i += 1024) sh_M3p[i] = M3p_[i];
    for (int i = tid; i < 256; i += 1024) {
        sh_ca[i] = ca_[i]; sh_cp[i] = cp_[i]; sh_cp3[i] = cp3_[i];
        sh_hv[i] = 0.f;
    }
    for (int i = tid; i < 128; i += 1024) {
        sh_sp0[i] = stat[((size_t)b * 3 + 1) * SS + i];
        sh_sp1[i] = stat[((size_t)b * 3 + 2) * SS + i];
        sh_lm[i]  = lm_[b * SS + i];
    }
    // quad-pack logit operands (step-invariant): 4 i per float4
    if (tid < 64) {
        int q = tid;
        qa1[q] = make_float4(M1a_[(4*q+0)*2], M1a_[(4*q+1)*2], M1a_[(4*q+2)*2], M1a_[(4*q+3)*2]);
        qa2[q] = make_float4(M1a_[(4*q+0)*2+1], M1a_[(4*q+1)*2+1], M1a_[(4*q+2)*2+1], M1a_[(4*q+3)*2+1]);
        qva[q] = make_float4(av[4*q+0], av[4*q+1], av[4*q+2], av[4*q+3]);
    } else if (tid < 128) {
        int q = tid - 64;
        qp1[q] = make_float4(M1p_[(4*q+0)*2], M1p_[(4*q+1)*2], M1p_[(4*q+2)*2], M1p_[(4*q+3)*2]);
        qp2[q] = make_float4(M1p_[(4*q+0)*2+1], M1p_[(4*q+1)*2+1], M1p_[(4*q+2)*2+1], M1p_[(4*q+3)*2+1]);
        qvp[q] = make_float4(pv[4*q+0], pv[4*q+1], pv[4*q+2], pv[4*q+3]);
    }
    if (tid == 0) {
        sh_scal[0] = dec_inp[b * 2 + 0];
        sh_scal[1] = dec_inp[b * 2 + 1];
        ycnt = 0;
    }
    const bool dz = (!allow_general) || (*flag == 0);
    __syncthreads();

    for (int t = 0; t < SS; ++t) {
        // ---- GRU gates (threads 0..255): h(t) from sh_gh + rank-2 gi fold
        if (tid < 256) {
            int k = tid;
            float d0 = sh_scal[0], d1 = sh_scal[1];
            float gr = fmaf(sh_G[k * 2],          d0, fmaf(sh_G[k * 2 + 1],          d1, sh_g0[k]));
            float gz = fmaf(sh_G[(k + 256) * 2],  d0, fmaf(sh_G[(k + 256) * 2 + 1],  d1, sh_g0[k + 256]));
            float gn = fmaf(sh_G[(k + 512) * 2],  d0, fmaf(sh_G[(k + 512) * 2 + 1],  d1, sh_g0[k + 512]));
            float r = 1.f / (1.f + expf(-(gr + sh_gh[k])));
            float z = 1.f / (1.f + expf(-(gz + sh_gh[k + 256])));
            float n = tanhf(gn + r * sh_gh[k + 512]);
            sh_hv[k] = (1.f - z) * n + z * sh_hv[k];
        }
        __syncthreads();      // h(t) visible to X and Y

        if (tid < 512) {
            // ===== X: sh_gh <- W_hh * h(t) + b_hh (for step t+1) =====
            if (t + 1 < SS) {
                const int xg = tid >> 4, xj = tid & 15;   // 32 row-groups x 16 lanes
                float4 hx0 = ((const float4*)sh_hv)[xj];
                float4 hx1 = ((const float4*)sh_hv)[xj + 16];
                float4 hx2 = ((const float4*)sh_hv)[xj + 32];
                float4 hx3 = ((const float4*)sh_hv)[xj + 48];
                // rows 0..127 from LDS cache
                #pragma unroll
                for (int k = 0; k < 4; ++k) {
                    int r = xg + 32 * k;
                    const float4* Wr = (const float4*)&sh_whh[r][0];
                    float4 w0 = Wr[xj];
                    float4 w1 = Wr[xj + 16];
                    float4 w2 = Wr[xj + 32];
                    float4 w3 = Wr[xj + 48];
                    float acc = 0.f;
                    acc = fmaf(w0.x, hx0.x, fmaf(w0.y, hx0.y, fmaf(w0.z, hx0.z, fmaf(w0.w, hx0.w, acc))));
                    acc = fmaf(w1.x, hx1.x, fmaf(w1.y, hx1.y, fmaf(w1.z, hx1.z, fmaf(w1.w, hx1.w, acc))));
                    acc = fmaf(w2.x, hx2.x, fmaf(w2.y, hx2.y, fmaf(w2.z, hx2.z, fmaf(w2.w, hx2.w, acc))));
                    acc = fmaf(w3.x, hx3.x, fmaf(w3.y, hx3.y, fmaf(w3.z, hx3.z, fmaf(w3.w, hx3.w, acc))));
                    acc += __shfl_xor(acc, 1, 16); acc += __shfl_xor(acc, 2, 16);
                    acc += __shfl_xor(acc, 4, 16); acc += __shfl_xor(acc, 8, 16);
                    if (xj == 0) sh_gh[r] = acc + sh_bhh[r];
                }
                // rows 128..767 streamed from L2
                #pragma unroll 2
                for (int k = 4; k < 24; ++k) {
                    int r = xg + 32 * k;
                    const float4* Wr = (const float4*)(Whh + (size_t)r * 256);
                    float4 w0 = Wr[xj];
                    float4 w1 = Wr[xj + 16];
                    float4 w2 = Wr[xj + 32];
                    float4 w3 = Wr[xj + 48];
                    float acc = 0.f;
                    acc = fmaf(w0.x, hx0.x, fmaf(w0.y, hx0.y, fmaf(w0.z, hx0.z, fmaf(w0.w, hx0.w, acc))));
                    acc = fmaf(w1.x, hx1.x, fmaf(w1.y, hx1.y, fmaf(w1.z, hx1.z, fmaf(w1.w, hx1.w, acc))));
                    acc = fmaf(w2.x, hx2.x, fmaf(w2.y, hx2.y, fmaf(w2.z, hx2.z, fmaf(w2.w, hx2.w, acc))));
                    acc = fmaf(w3.x, hx3.x, fmaf(w3.y, hx3.y, fmaf(w3.z, hx3.z, fmaf(w3.w, hx3.w, acc))));
                    acc += __shfl_xor(acc, 1, 16); acc += __shfl_xor(acc, 2, 16);
                    acc += __shfl_xor(acc, 4, 16); acc += __shfl_xor(acc, 8, 16);
                    if (xj == 0) sh_gh[r] = acc + sh_bhh[r];
                }
            }
        } else {
            // ===== Y: t1 -> attn -> softmax -> ptr -> argmax =====
            const int yt = tid - 512;
            const int ybase = t * 25;

            // Y1: t1 = A3 * h (stream A3 from L2) (+ ca on zero path)
            {
                const int yq = yt >> 4, yj = yt & 15;   // 32 row-groups
                float4 hx0 = ((const float4*)sh_hv)[yj];
                float4 hx1 = ((const float4*)sh_hv)[yj + 16];
                float4 hx2 = ((const float4*)sh_hv)[yj + 32];
                float4 hx3 = ((const float4*)sh_hv)[yj + 48];
                #pragma unroll 2
                for (int k = 0; k < 8; ++k) {
                    int r = yq + 32 * k;
                    const float4* Wr = (const float4*)(aW + (size_t)r * 768 + 512);
                    float4 w0 = Wr[yj];
                    float4 w1 = Wr[yj + 16];
                    float4 w2 = Wr[yj + 32];
                    float4 w3 = Wr[yj + 48];
                    float acc = 0.f;
                    acc = fmaf(w0.x, hx0.x, fmaf(w0.y, hx0.y, fmaf(w0.z, hx0.z, fmaf(w0.w, hx0.w, acc))));
                    acc = fmaf(w1.x, hx1.x, fmaf(w1.y, hx1.y, fmaf(w1.z, hx1.z, fmaf(w1.w, hx1.w, acc))));
                    acc = fmaf(w2.x, hx2.x, fmaf(w2.y, hx2.y, fmaf(w2.z, hx2.z, fmaf(w2.w, hx2.w, acc))));
                    acc = fmaf(w3.x, hx3.x, fmaf(w3.y, hx3.y, fmaf(w3.z, hx3.z, fmaf(w3.w, hx3.w, acc))));
                    acc += __shfl_xor(acc, 1, 16); acc += __shfl_xor(acc, 2, 16);
                    acc += __shfl_xor(acc, 4, 16); acc += __shfl_xor(acc, 8, 16);
                    if (yj == 0) sh_t1[r] = acc + (dz ? sh_ca[r] : 0.f);
                }
            }
            ybar(&ycnt, true, ybase + 8);

            // Y2: attn logits (4 threads per s, quad-vectorized)
            {
                int s = yt >> 2, g = yt & 3;
                float acc = 0.f;
                if (dz) {
                    float s0 = sh_sp0[s], s1 = sh_sp1[s];
                    #pragma unroll 4
                    for (int q = g; q < 64; q += 4) {
                        float4 A1 = qa1[q], A2 = qa2[q], V = qva[q];
                        float4 T = ((const float4*)sh_t1)[q];
                        acc = fmaf(V.x, tanh_fast(fmaf(A1.x, s0, fmaf(A2.x, s1, T.x))), acc);
                        acc = fmaf(V.y, tanh_fast(fmaf(A1.y, s0, fmaf(A2.y, s1, T.y))), acc);
                        acc = fmaf(V.z, tanh_fast(fmaf(A1.z, s0, fmaf(A2.z, s1, T.z))), acc);
                        acc = fmaf(V.w, tanh_fast(fmaf(A1.w, s0, fmaf(A2.w, s1, T.w))), acc);
                    }
                } else {
                    const float* bb = basea + ((size_t)b * SS + s) * HH;
                    #pragma unroll 4
                    for (int q = g; q < 64; q += 4) {
                        float4 V = qva[q];
                        float4 T = ((const float4*)sh_t1)[q];
                        float4 B = *(const float4*)(bb + q * 4);
                        acc = fmaf(V.x, tanh_fast(B.x + T.x), acc);
                        acc = fmaf(V.y, tanh_fast(B.y + T.y), acc);
                        acc = fmaf(V.z, tanh_fast(B.z + T.z), acc);
                        acc = fmaf(V.w, tanh_fast(B.w + T.w), acc);
                    }
                }
                acc += __shfl_xor(acc, 1, 4); acc += __shfl_xor(acc, 2, 4);
                if (g == 0) sh_a[s] = acc;
            }
            ybar(&ycnt, true, ybase + 16);

            // Y3: softmax + context + t2 fold (wave 8 only)
            if (yt < 64) {
                int ln = yt;
                float v0 = sh_a[ln], v1 = sh_a[ln + 64];
                float m = fmaxf(v0, v1);
                for (int msk = 1; msk < 64; msk <<= 1) m = fmaxf(m, __shfl_xor(m, msk, 64));
                float e0 = expf(v0 - m), e1 = expf(v1 - m);
                float S = e0 + e1;
                float c0 = e0 * sh_sp0[ln] + e1 * sh_sp0[ln + 64];
                float c1 = e0 * sh_sp1[ln] + e1 * sh_sp1[ln + 64];
                for (int msk = 1; msk < 64; msk <<= 1) {
                    S  += __shfl_xor(S,  msk, 64);
                    c0 += __shfl_xor(c0, msk, 64);
                    c1 += __shfl_xor(c1, msk, 64);
                }
                float C0 = c0 / S, C1 = c1 / S;
                #pragma unroll
                for (int q = 0; q < 4; ++q) {
                    int k2 = ln + 64 * q;
                    float v = fmaf(sh_M3p[k2 * 2], C0, fmaf(sh_M3p[k2 * 2 + 1], C1, sh_cp3[k2]));
                    sh_t1[k2] = v + (dz ? sh_cp[k2] : 0.f);
                }
                ybar(&ycnt, true, ybase + 17);
            } else {
                ybar(&ycnt, false, ybase + 17);
            }

            // Y4: ptr logits (quad-vectorized)
            {
                int s = yt >> 2, g = yt & 3;
                float acc = 0.f;
                if (dz) {
                    float s0 = sh_sp0[s], s1 = sh_sp1[s];
                    #pragma unroll 4
                    for (int q = g; q < 64; q += 4) {
                        float4 A1 = qp1[q], A2 = qp2[q], V = qvp[q];
                        float4 T = ((const float4*)sh_t1)[q];
                        acc = fmaf(V.x, tanh_fast(fmaf(A1.x, s0, fmaf(A2.x, s1, T.x))), acc);
                        acc = fmaf(V.y, tanh_fast(fmaf(A1.y, s0, fmaf(A2.y, s1, T.y))), acc);
                        acc = fmaf(V.z, tanh_fast(fmaf(A1.z, s0, fmaf(A2.z, s1, T.z))), acc);
                        acc = fmaf(V.w, tanh_fast(fmaf(A1.w, s0, fmaf(A2.w, s1, T.w))), acc);
                    }
                } else {
                    const float* bb = basep + ((size_t)b * SS + s) * HH;
                    #pragma unroll 4
                    for (int q = g; q < 64; q += 4) {
                        float4 V = qvp[q];
                        float4 T = ((const float4*)sh_t1)[q];
                        float4 B = *(const float4*)(bb + q * 4);
                        acc = fmaf(V.x, tanh_fast(B.x + T.x), acc);
                        acc = fmaf(V.y, tanh_fast(B.y + T.y), acc);
                        acc = fmaf(V.z, tanh_fast(B.z + T.z), acc);
                        acc = fmaf(V.w, tanh_fast(B.w + T.w), acc);
                    }
                }
                acc += __shfl_xor(acc, 1, 4); acc += __shfl_xor(acc, 2, 4);
                if (g == 0) sh_a[s] = acc;
            }
            ybar(&ycnt, true, ybase + 25);

            // Y5: masked argmax + logp + dec_in update (wave 8 only)
            if (yt < 64) {
                int ln = yt;
                float l0 = sh_a[ln] + sh_lm[ln];
                float l1 = sh_a[ln + 64] + sh_lm[ln + 64];
                float v; int idx;
                if (l0 >= l1) { v = l0; idx = ln; } else { v = l1; idx = ln + 64; }
                for (int msk = 1; msk < 64; msk <<= 1) {
                    float ov = __shfl_xor(v, msk, 64);
                    int   oi = __shfl_xor(idx, msk, 64);
                    if (ov > v || (ov == v && oi < idx)) { v = ov; idx = oi; }
                }
                float S = expf(l0 - v) + expf(l1 - v);
                for (int msk = 1; msk < 64; msk <<= 1) S += __shfl_xor(S, msk, 64);
                if (ln == 0) {
                    out[b * SS + t] = (float)idx;
                    out[BB * SS + b * SS + t] = -logf(S);
                    sh_scal[0] = sh_sp0[idx];
                    sh_scal[1] = sh_sp1[idx];
                }
            }
        }
        __syncthreads();      // gh(t+1), dec_in, Y buffers all settled
    }
}

extern "C" void kernel_launch(void* const* d_in, const int* in_sizes, int n_in,
                              void* d_out, int out_size, void* d_ws, size_t ws_size,
                              hipStream_t stream) {
    const float* stat  = (const float*)d_in[0];
    const float* dyn   = (const float*)d_in[1];
    const float* decin = (const float*)d_in[2];
    const float* esW   = (const float*)d_in[3];
    const float* esb   = (const float*)d_in[4];
    const float* edW   = (const float*)d_in[5];
    const float* edb   = (const float*)d_in[6];
    const float* dW    = (const float*)d_in[7];
    const float* db    = (const float*)d_in[8];
    const float* Wih   = (const float*)d_in[9];
    const float* Whh   = (const float*)d_in[10];
    const float* bih   = (const float*)d_in[11];
    const float* bhh   = (const float*)d_in[12];
    const float* av    = (const float*)d_in[13];
    const float* aW    = (const float*)d_in[14];
    const float* pv    = (const float*)d_in[15];
    const float* pW    = (const float*)d_in[16];
    float* wsf = (float*)d_ws;
    int* flag  = (int*)d_ws;
    float* out = (float*)d_out;

    int allow_general = (ws_size >= (size_t)OFF_END * 4) ? 1 : 0;

    hipMemsetAsync(d_ws, 0, 256, stream);
    hipLaunchKernelGGL(k1_logmask, dim3(64), dim3(256), 0, stream, dyn, wsf + OFF_LM, flag);
    hipLaunchKernelGGL(k0a_folds, dim3(18), dim3(256), 0, stream,
                       Wih, bih, dW, db, aW, pW, esW, esb, edb, wsf);
    if (allow_general) {
        hipLaunchKernelGGL(k0b_m2, dim3(384), dim3(256), 0, stream, aW, pW, edW, wsf, flag);
        hipLaunchKernelGGL(k2_bases, dim3(256), dim3(256), 0, stream, stat, dyn, wsf, flag);
    }
    hipLaunchKernelGGL(k3_seq, dim3(128), dim3(1024), 0, stream,
                       stat, decin, Whh, bhh, aW, av, pv, wsf, allow_general, out);
}